// Round 3
// baseline (8346.033 us; speedup 1.0000x reference)
//
#include <hip/hip_runtime.h>
#include <math.h>

static __device__ __forceinline__ float silu_f(float x){ return x / (1.f + expf(-x)); }
static __device__ __forceinline__ float softplus_f(float x){ return (x > 20.f) ? x : log1pf(expf(x)); }

// ---------------- workspace layout (float offsets) ----------------
// stats region [0,8192)
#define OFF_WDT    8192u        /* 49,152 (3,128,128) — written after fcat is dead */
#define OFF_FCAT   8192u        /* 9,830,400  (10,240,64,64) */
#define OFF_DECIN  5251072u     /* 2,621,440 reuse fcat region (fcat dead) */
#define OFF_DOWN   9838592u     /* 3,932,160  (10,384,32,32) */
#define OFF_DECOUT 9838592u     /* 1,310,720  reuse down region */
#define OFF_UC0    11149312u    /* 655,360 */
#define OFF_UC1    11804672u    /* 655,360 */
#define OFF_TOK    13770752u    /* 7,864,320  (10240,12,64) */
#define OFF_FUS0   13770752u    /* 2,621,440  reuse tok region */
#define OFF_FUS1   16392192u    /* 2,621,440 */

// ---------------- K1: f = concat([high, features + tile(high,4)]) ----------------
__global__ __launch_bounds__(256) void k_fcat(const float* __restrict__ feat,
                                              const float* __restrict__ high,
                                              float* __restrict__ out){
    int idx = blockIdx.x*256 + threadIdx.x;          // total 9,830,400
    if (idx >= 9830400) return;
    int b   = idx / 983040;
    int rem = idx - b*983040;
    int c   = rem >> 12;
    int hw  = rem & 4095;
    float v;
    if (c < 48){
        v = high[((size_t)b*48 + c)*4096 + hw];
    } else {
        int c2 = c - 48;
        v = feat[((size_t)b*192 + c2)*4096 + hw] + high[((size_t)b*48 + (c2 % 48))*4096 + hw];
    }
    out[idx] = v;
}

// ---------------- generic BN stats: one block per channel ----------------
__global__ __launch_bounds__(256) void k_bn_stats(const float* __restrict__ x,
                                                  const float* __restrict__ g,
                                                  const float* __restrict__ b,
                                                  float* __restrict__ scale,
                                                  float* __restrict__ shift,
                                                  int C, int hwshift, int N){
    int c = blockIdx.x;
    int HW = 1 << hwshift;
    int total = N << hwshift;
    float s = 0.f, s2 = 0.f;
    for (int i = threadIdx.x; i < total; i += 256){
        int n  = i >> hwshift;
        int hw = i & (HW - 1);
        float v = x[((size_t)n*C + c)*HW + hw];
        s += v; s2 = fmaf(v, v, s2);
    }
    __shared__ float rs[256], rq[256];
    rs[threadIdx.x] = s; rq[threadIdx.x] = s2;
    __syncthreads();
    for (int off = 128; off; off >>= 1){
        if (threadIdx.x < off){ rs[threadIdx.x] += rs[threadIdx.x+off]; rq[threadIdx.x] += rq[threadIdx.x+off]; }
        __syncthreads();
    }
    if (threadIdx.x == 0){
        float inv = 1.f / (float)total;
        float m   = rs[0]*inv;
        float var = rq[0]*inv - m*m;
        if (var < 0.f) var = 0.f;
        float sc = g[c] * rsqrtf(var + 1e-5f);
        scale[c] = sc;
        shift[c] = b[c] - m*sc;
    }
}

// ---------------- in-place affine + SiLU ----------------
__global__ __launch_bounds__(256) void k_affine_silu(float* __restrict__ x,
                                                     const float* __restrict__ scale,
                                                     const float* __restrict__ shift,
                                                     int C, int hwshift, int total){
    int idx = blockIdx.x*256 + threadIdx.x;
    if (idx >= total) return;
    int c = (idx >> hwshift) % C;
    float v = fmaf(x[idx], scale[c], shift[c]);
    x[idx] = silu_f(v);
}

// ---------------- down conv: 3x3 s2 g12, BN(input) fused ----------------
__global__ __launch_bounds__(256) void k_down(const float* __restrict__ fcat,
                                              const float* __restrict__ w,
                                              const float* __restrict__ sc,
                                              const float* __restrict__ sh,
                                              float* __restrict__ out){
    int idx = blockIdx.x*256 + threadIdx.x;          // 3,932,160 = 10*384*1024
    if (idx >= 3932160) return;
    int b   = idx / 393216;
    int rem = idx - b*393216;
    int o   = rem >> 10;
    int hw  = rem & 1023;
    int oh = hw >> 5, ow = hw & 31;
    int ibase = (o >> 5) * 20;                        // group = o/32, 20 in-ch per group
    const float* wt = w + (size_t)o*180;              // 20*9
    float acc = 0.f;
    for (int ci = 0; ci < 20; ++ci){
        int c = ibase + ci;
        const float* inp = fcat + ((size_t)b*240 + c)*4096;
        float s = sc[c], t = sh[c];
        const float* wr = wt + ci*9;
        #pragma unroll
        for (int kh = 0; kh < 3; ++kh){
            int ih = oh*2 + kh - 1;
            if (ih < 0 || ih >= 64) continue;
            #pragma unroll
            for (int kw = 0; kw < 3; ++kw){
                int iw = ow*2 + kw - 1;
                if (iw < 0 || iw >= 64) continue;
                acc += fmaf(inp[ih*64 + iw], s, t) * wr[kh*3 + kw];
            }
        }
    }
    out[idx] = acc;
}

// ---------------- emb conv: 3x3 g12 + bias, writes token layout ----------------
__global__ __launch_bounds__(256) void k_emb(const float* __restrict__ down_act,
                                             const float* __restrict__ w,
                                             const float* __restrict__ bias,
                                             float* __restrict__ tok){
    int idx = blockIdx.x*256 + threadIdx.x;          // 7,864,320 = 10*768*1024
    if (idx >= 7864320) return;
    int b   = idx / 786432;
    int rem = idx - b*786432;
    int c   = rem >> 10;
    int hw  = rem & 1023;
    int oh = hw >> 5, ow = hw & 31;
    int ibase = (c >> 6) * 32;                        // group = c/64, 32 in-ch
    const float* wt = w + (size_t)c*288;              // 32*9
    float acc = bias[c];
    for (int ci = 0; ci < 32; ++ci){
        const float* inp = down_act + ((size_t)b*384 + ibase + ci)*1024;
        const float* wr = wt + ci*9;
        #pragma unroll
        for (int kh = 0; kh < 3; ++kh){
            int ih = oh + kh - 1;
            if (ih < 0 || ih >= 32) continue;
            #pragma unroll
            for (int kw = 0; kw < 3; ++kw){
                int iw = ow + kw - 1;
                if (iw < 0 || iw >= 32) continue;
                acc = fmaf(inp[ih*32 + iw], wr[kh*3 + kw], acc);
            }
        }
    }
    tok[((size_t)(b*1024 + hw))*768 + c] = acc;
}

// ---------------- wave-64 reductions ----------------
static __device__ __forceinline__ float wsum64(float v){
    #pragma unroll
    for (int m = 32; m; m >>= 1) v += __shfl_xor(v, m, 64);
    return v;
}

// ---------------- precompute W_dt[chunk][ch][d] = sum_r dt_w[chunk][ch][r]*xproj_w[chunk][r][d] ----------------
__global__ __launch_bounds__(256) void k_wdt(const float* __restrict__ dt_w,
                                             const float* __restrict__ xproj_w,
                                             float* __restrict__ Wdt){
    int idx = blockIdx.x*256 + threadIdx.x;          // 49,152
    if (idx >= 49152) return;
    int chunk = idx >> 14;
    int rem   = idx & 16383;
    int ch    = rem >> 7;
    int d     = rem & 127;
    const float* dwr = dt_w + (size_t)(chunk*128 + ch)*32;
    const float* xw  = xproj_w + (size_t)chunk*8192 + d;   // row r at r*128+d
    float acc = 0.f;
    #pragma unroll
    for (int r = 0; r < 32; ++r) acc = fmaf(dwr[r], xw[(size_t)r*128], acc);
    Wdt[idx] = acc;
}

// ---------------- fused mamba: LN1 + in-proj + dt/BC + scan + gate + out-proj + LN2 + transpose ----------------
// one block = one token, 128 threads = one channel each, state in registers,
// all cross-phase arrays in LDS (NO runtime-indexed register arrays -> no scratch)
__global__ __launch_bounds__(128, 4) void k_mamba2(const float* __restrict__ tok,  // [10240][768]
                                                const float* __restrict__ in_w,    // (3,256,64)
                                                const float* __restrict__ conv_w,  // (3,128)
                                                const float* __restrict__ conv_b,
                                                const float* __restrict__ xproj_w, // (3,64,128)
                                                const float* __restrict__ Wdt,     // (3,128,128)
                                                const float* __restrict__ dt_b,    // (3,128)
                                                const float* __restrict__ A_log,   // (3,128,16)
                                                const float* __restrict__ Dp,      // (3,128)
                                                const float* __restrict__ out_w,   // (3,64,128)
                                                const float* __restrict__ ln1_g,
                                                const float* __restrict__ ln1_b,
                                                const float* __restrict__ ln2_g,
                                                const float* __restrict__ ln2_b,
                                                float* __restrict__ dec_in){       // (10,256,1024)
    int token = blockIdx.x;
    int tid   = threadIdx.x;           // 0..127
    int lane  = tid & 63, wv = tid >> 6;
    int ch    = tid;

    __shared__ float xs[12][64];       // LN1'd tokens
    __shared__ float raw[4][64];       // pre-LN rows 8..11 (mfi)
    __shared__ float xi_s[12][128];
    __shared__ float dtv_s[12][128];   // dt values (LDS, conflict-free: same s, consecutive ch)
    __shared__ float bc[12][32];
    __shared__ float yz[4][128];

    // ---- load + LN1 (wave per row) ----
    const float* trow = tok + (size_t)token*768;
    for (int r = wv; r < 12; r += 2){
        float v = trow[r*64 + lane];
        if (r >= 8) raw[r-8][lane] = v;
        float m  = wsum64(v) * (1.f/64.f);
        float dv = v - m;
        float var = wsum64(dv*dv) * (1.f/64.f);
        xs[r][lane] = dv*rsqrtf(var + 1e-5f)*ln1_g[lane] + ln1_b[lane];
    }
    __syncthreads();

    // ---- in-proj (+conv scale + silu) for all 12 steps; z for steps 8..11 ----
    float zrow[4];
    for (int chunk = 0; chunk < 3; ++chunk){
        const float4* wr = (const float4*)(in_w + ((size_t)chunk*256 + ch)*64);
        float a0=0.f, a1=0.f, a2=0.f, a3=0.f;
        int s0 = chunk*4;
        #pragma unroll
        for (int j = 0; j < 16; ++j){
            float4 w = wr[j];
            int d = j*4;
            a0 = fmaf(xs[s0+0][d], w.x, a0); a0 = fmaf(xs[s0+0][d+1], w.y, a0);
            a0 = fmaf(xs[s0+0][d+2], w.z, a0); a0 = fmaf(xs[s0+0][d+3], w.w, a0);
            a1 = fmaf(xs[s0+1][d], w.x, a1); a1 = fmaf(xs[s0+1][d+1], w.y, a1);
            a1 = fmaf(xs[s0+1][d+2], w.z, a1); a1 = fmaf(xs[s0+1][d+3], w.w, a1);
            a2 = fmaf(xs[s0+2][d], w.x, a2); a2 = fmaf(xs[s0+2][d+1], w.y, a2);
            a2 = fmaf(xs[s0+2][d+2], w.z, a2); a2 = fmaf(xs[s0+2][d+3], w.w, a2);
            a3 = fmaf(xs[s0+3][d], w.x, a3); a3 = fmaf(xs[s0+3][d+1], w.y, a3);
            a3 = fmaf(xs[s0+3][d+2], w.z, a3); a3 = fmaf(xs[s0+3][d+3], w.w, a3);
        }
        float cw = conv_w[chunk*128 + ch], cb = conv_b[chunk*128 + ch];
        xi_s[s0+0][ch] = silu_f(fmaf(a0, cw, cb));
        xi_s[s0+1][ch] = silu_f(fmaf(a1, cw, cb));
        xi_s[s0+2][ch] = silu_f(fmaf(a2, cw, cb));
        xi_s[s0+3][ch] = silu_f(fmaf(a3, cw, cb));
    }
    {   // z (chunk 2 only, rows 128+ch)
        const float4* wr = (const float4*)(in_w + ((size_t)2*256 + 128 + ch)*64);
        float a0=0.f, a1=0.f, a2=0.f, a3=0.f;
        #pragma unroll
        for (int j = 0; j < 16; ++j){
            float4 w = wr[j];
            int d = j*4;
            a0 = fmaf(xs[8][d], w.x, a0); a0 = fmaf(xs[8][d+1], w.y, a0);
            a0 = fmaf(xs[8][d+2], w.z, a0); a0 = fmaf(xs[8][d+3], w.w, a0);
            a1 = fmaf(xs[9][d], w.x, a1); a1 = fmaf(xs[9][d+1], w.y, a1);
            a1 = fmaf(xs[9][d+2], w.z, a1); a1 = fmaf(xs[9][d+3], w.w, a1);
            a2 = fmaf(xs[10][d], w.x, a2); a2 = fmaf(xs[10][d+1], w.y, a2);
            a2 = fmaf(xs[10][d+2], w.z, a2); a2 = fmaf(xs[10][d+3], w.w, a2);
            a3 = fmaf(xs[11][d], w.x, a3); a3 = fmaf(xs[11][d+1], w.y, a3);
            a3 = fmaf(xs[11][d+2], w.z, a3); a3 = fmaf(xs[11][d+3], w.w, a3);
        }
        zrow[0] = silu_f(a0); zrow[1] = silu_f(a1); zrow[2] = silu_f(a2); zrow[3] = silu_f(a3);
    }
    __syncthreads();

    // ---- dt -> LDS (via combined W_dt) ----
    for (int chunk = 0; chunk < 3; ++chunk){
        const float4* wr = (const float4*)(Wdt + ((size_t)chunk*128 + ch)*128);
        float a0=0.f, a1=0.f, a2=0.f, a3=0.f;
        int s0 = chunk*4;
        #pragma unroll
        for (int j = 0; j < 32; ++j){
            float4 w = wr[j];
            int d = j*4;
            a0 = fmaf(xi_s[s0+0][d], w.x, a0); a0 = fmaf(xi_s[s0+0][d+1], w.y, a0);
            a0 = fmaf(xi_s[s0+0][d+2], w.z, a0); a0 = fmaf(xi_s[s0+0][d+3], w.w, a0);
            a1 = fmaf(xi_s[s0+1][d], w.x, a1); a1 = fmaf(xi_s[s0+1][d+1], w.y, a1);
            a1 = fmaf(xi_s[s0+1][d+2], w.z, a1); a1 = fmaf(xi_s[s0+1][d+3], w.w, a1);
            a2 = fmaf(xi_s[s0+2][d], w.x, a2); a2 = fmaf(xi_s[s0+2][d+1], w.y, a2);
            a2 = fmaf(xi_s[s0+2][d+2], w.z, a2); a2 = fmaf(xi_s[s0+2][d+3], w.w, a2);
            a3 = fmaf(xi_s[s0+3][d], w.x, a3); a3 = fmaf(xi_s[s0+3][d+1], w.y, a3);
            a3 = fmaf(xi_s[s0+3][d+2], w.z, a3); a3 = fmaf(xi_s[s0+3][d+3], w.w, a3);
        }
        float db = dt_b[chunk*128 + ch];
        dtv_s[s0+0][ch] = softplus_f(a0 + db);
        dtv_s[s0+1][ch] = softplus_f(a1 + db);
        dtv_s[s0+2][ch] = softplus_f(a2 + db);
        dtv_s[s0+3][ch] = softplus_f(a3 + db);
    }

    // ---- B and C (384 outputs, 3 per thread) ----
    for (int i = tid; i < 384; i += 128){
        int s = i >> 5, e = i & 31;
        int chunk = s >> 2;
        const float4* wr = (const float4*)(xproj_w + ((size_t)chunk*64 + 32 + e)*128);
        float acc = 0.f;
        #pragma unroll
        for (int j = 0; j < 32; ++j){
            float4 w = wr[j];
            int d = j*4;
            acc = fmaf(xi_s[s][d], w.x, acc); acc = fmaf(xi_s[s][d+1], w.y, acc);
            acc = fmaf(xi_s[s][d+2], w.z, acc); acc = fmaf(xi_s[s][d+3], w.w, acc);
        }
        bc[s][e] = acc;
    }
    __syncthreads();

    // ---- scan (state + A in registers, all static indices) ----
    float st[16];
    #pragma unroll
    for (int n = 0; n < 16; ++n) st[n] = 0.f;
    for (int chunk = 0; chunk < 3; ++chunk){
        float a[16];
        const float* ar = A_log + ((size_t)chunk*128 + ch)*16;
        #pragma unroll
        for (int n = 0; n < 16; ++n) a[n] = -expf(ar[n]);
        #pragma unroll
        for (int t = 0; t < 4; ++t){
            int s = chunk*4 + t;
            float dtc = dtv_s[s][ch];
            float xiv = xi_s[s][ch];
            float dx  = dtc * xiv;
            if (chunk < 2){
                #pragma unroll
                for (int n = 0; n < 16; ++n)
                    st[n] = fmaf(st[n], expf(dtc*a[n]), dx*bc[s][n]);
            } else {
                float y = 0.f;
                #pragma unroll
                for (int n = 0; n < 16; ++n){
                    st[n] = fmaf(st[n], expf(dtc*a[n]), dx*bc[s][n]);
                    y = fmaf(st[n], bc[s][16+n], y);
                }
                y = fmaf(Dp[2*128 + ch], xiv, y);
                yz[t][ch] = y * zrow[t];
            }
        }
    }
    __syncthreads();

    // ---- out-proj + LN2 + transposed store ----
    int b = token >> 10, hw = token & 1023;
    #pragma unroll
    for (int p = 0; p < 2; ++p){
        int l = wv*2 + p;
        const float4* wr = (const float4*)(out_w + ((size_t)2*64 + lane)*128);
        float acc = 0.f;
        #pragma unroll
        for (int j = 0; j < 32; ++j){
            float4 w = wr[j];
            int d = j*4;
            acc = fmaf(yz[l][d], w.x, acc); acc = fmaf(yz[l][d+1], w.y, acc);
            acc = fmaf(yz[l][d+2], w.z, acc); acc = fmaf(yz[l][d+3], w.w, acc);
        }
        float v = raw[l][lane] + acc;
        float m  = wsum64(v) * (1.f/64.f);
        float dv = v - m;
        float var = wsum64(dv*dv) * (1.f/64.f);
        float r = dv*rsqrtf(var + 1e-5f)*ln2_g[lane] + ln2_b[lane];
        dec_in[(size_t)b*262144 + (size_t)(l*64 + lane)*1024 + hw] = r;
    }
}

// ---------------- dec conv: 3x3 g4 + bias ----------------
__global__ __launch_bounds__(256) void k_dec(const float* __restrict__ dec_in,
                                             const float* __restrict__ w,
                                             const float* __restrict__ bias,
                                             float* __restrict__ out){
    int idx = blockIdx.x*256 + threadIdx.x;          // 1,310,720 = 10*128*1024
    if (idx >= 1310720) return;
    int b   = idx / 131072;
    int rem = idx - b*131072;
    int o   = rem >> 10;
    int hw  = rem & 1023;
    int oh = hw >> 5, ow = hw & 31;
    int ibase = (o >> 5) * 64;
    const float* wt = w + (size_t)o*576;             // 64*9
    float acc = bias[o];
    for (int ci = 0; ci < 64; ++ci){
        const float* inp = dec_in + ((size_t)b*256 + ibase + ci)*1024;
        const float* wr = wt + ci*9;
        #pragma unroll
        for (int kh = 0; kh < 3; ++kh){
            int ih = oh + kh - 1;
            if (ih < 0 || ih >= 32) continue;
            #pragma unroll
            for (int kw = 0; kw < 3; ++kw){
                int iw = ow + kw - 1;
                if (iw < 0 || iw >= 32) continue;
                acc = fmaf(inp[ih*32 + iw], wr[kh*3 + kw], acc);
            }
        }
    }
    out[idx] = acc;
}

// ---------------- up 1x1 convs (both branches), at 32x32 ----------------
__global__ __launch_bounds__(256) void k_up(const float* __restrict__ dec_out,
                                            const float* __restrict__ w0,
                                            const float* __restrict__ w1,
                                            float* __restrict__ uc0,
                                            float* __restrict__ uc1){
    int idx = blockIdx.x*256 + threadIdx.x;          // 1,310,720 = 2*10*64*1024
    if (idx >= 1310720) return;
    int r = idx >= 655360;
    int j = idx - r*655360;
    int b   = j / 65536;
    int rem = j - b*65536;
    int o   = rem >> 10;
    int hw  = rem & 1023;
    const float* w = r ? w1 : w0;
    const float* in = dec_out + (size_t)b*131072 + (size_t)(r*64)*1024 + hw;
    float acc = 0.f;
    #pragma unroll
    for (int i = 0; i < 64; ++i) acc = fmaf(in[(size_t)i*1024], w[o*64 + i], acc);
    (r ? uc1 : uc0)[j] = acc;
}

// ---------------- fuse conv: 3x3, input = [upsampled uc_act(64) ; fid(64)] ----------------
__global__ __launch_bounds__(256) void k_fus(const float* __restrict__ uc_act,
                                             const float* __restrict__ fid,
                                             const float* __restrict__ w,
                                             const float* __restrict__ bias,
                                             float* __restrict__ out){
    int idx = blockIdx.x*256 + threadIdx.x;          // 2,621,440 = 10*64*4096
    if (idx >= 2621440) return;
    int b   = idx >> 18;
    int rem = idx & 262143;
    int o   = rem >> 12;
    int hw  = rem & 4095;
    int oh = hw >> 6, ow = hw & 63;
    const float* wt = w + (size_t)o*1152;            // 128*9
    float acc = bias[o];
    for (int i = 0; i < 64; ++i){
        const float* up = uc_act + ((size_t)b*64 + i)*1024;
        const float* wr = wt + i*9;
        #pragma unroll
        for (int kh = 0; kh < 3; ++kh){
            int ih = oh + kh - 1;
            if (ih < 0 || ih >= 64) continue;
            const float* uprow = up + (ih >> 1)*32;
            #pragma unroll
            for (int kw = 0; kw < 3; ++kw){
                int iw = ow + kw - 1;
                if (iw < 0 || iw >= 64) continue;
                acc = fmaf(uprow[iw >> 1], wr[kh*3 + kw], acc);
            }
        }
    }
    for (int i = 0; i < 64; ++i){
        const float* fp = fid + ((size_t)b*64 + i)*4096;
        const float* wr = wt + (64 + i)*9;
        #pragma unroll
        for (int kh = 0; kh < 3; ++kh){
            int ih = oh + kh - 1;
            if (ih < 0 || ih >= 64) continue;
            #pragma unroll
            for (int kw = 0; kw < 3; ++kw){
                int iw = ow + kw - 1;
                if (iw < 0 || iw >= 64) continue;
                acc = fmaf(fp[ih*64 + iw], wr[kh*3 + kw], acc);
            }
        }
    }
    out[idx] = acc;
}

// ---------------- final 1x1 conv + SiLU ----------------
__global__ __launch_bounds__(256) void k_final(const float* __restrict__ f0,
                                               const float* __restrict__ f1,
                                               const float* __restrict__ w,
                                               const float* __restrict__ bias,
                                               float* __restrict__ out){
    int idx = blockIdx.x*256 + threadIdx.x;          // 2,621,440 = 10*64*4096
    if (idx >= 2621440) return;
    int b   = idx >> 18;
    int rem = idx & 262143;
    int o   = rem >> 12;
    int hw  = rem & 4095;
    const float* p0 = f0 + (size_t)b*262144 + hw;
    const float* p1 = f1 + (size_t)b*262144 + hw;
    const float* w0 = w + o*128;
    float acc = bias[o];
    #pragma unroll
    for (int i = 0; i < 64; ++i) acc = fmaf(p0[(size_t)i*4096], w0[i], acc);
    #pragma unroll
    for (int i = 0; i < 64; ++i) acc = fmaf(p1[(size_t)i*4096], w0[64 + i], acc);
    out[idx] = silu_f(acc);
}

extern "C" void kernel_launch(void* const* d_in, const int* in_sizes, int n_in,
                              void* d_out, int out_size, void* d_ws, size_t ws_size,
                              hipStream_t stream) {
    const float* features = (const float*)d_in[0];
    const float* high     = (const float*)d_in[1];
    const float* fid0     = (const float*)d_in[2];
    const float* fid1     = (const float*)d_in[3];
    const float* bn_in_g  = (const float*)d_in[4];
    const float* bn_in_b  = (const float*)d_in[5];
    const float* down_w   = (const float*)d_in[6];
    const float* down_bn_g= (const float*)d_in[7];
    const float* down_bn_b= (const float*)d_in[8];
    const float* emb_w    = (const float*)d_in[9];
    const float* emb_b    = (const float*)d_in[10];
    const float* ln1_g    = (const float*)d_in[11];
    const float* ln1_b    = (const float*)d_in[12];
    const float* m_in_w   = (const float*)d_in[13];
    const float* m_conv_w = (const float*)d_in[14];
    const float* m_conv_b = (const float*)d_in[15];
    const float* m_xproj_w= (const float*)d_in[16];
    const float* m_dt_w   = (const float*)d_in[17];
    const float* m_dt_b   = (const float*)d_in[18];
    const float* m_A_log  = (const float*)d_in[19];
    const float* m_D      = (const float*)d_in[20];
    const float* m_out_w  = (const float*)d_in[21];
    const float* ln2_g    = (const float*)d_in[22];
    const float* ln2_b    = (const float*)d_in[23];
    const float* dec_w    = (const float*)d_in[24];
    const float* dec_b    = (const float*)d_in[25];
    const float* up0_w    = (const float*)d_in[26];
    const float* up0_bn_g = (const float*)d_in[27];
    const float* up0_bn_b = (const float*)d_in[28];
    const float* up1_w    = (const float*)d_in[29];
    const float* up1_bn_g = (const float*)d_in[30];
    const float* up1_bn_b = (const float*)d_in[31];
    const float* fus0_w   = (const float*)d_in[32];
    const float* fus0_b   = (const float*)d_in[33];
    const float* fus0_bn_g= (const float*)d_in[34];
    const float* fus0_bn_b= (const float*)d_in[35];
    const float* fus1_w   = (const float*)d_in[36];
    const float* fus1_b   = (const float*)d_in[37];
    const float* fus1_bn_g= (const float*)d_in[38];
    const float* fus1_bn_b= (const float*)d_in[39];
    const float* outf_w   = (const float*)d_in[40];
    const float* outf_b   = (const float*)d_in[41];

    float* ws = (float*)d_ws;
    float* out = (float*)d_out;

    float* st_in_sc  = ws + 0;    float* st_in_sh  = ws + 256;
    float* st_dn_sc  = ws + 512;  float* st_dn_sh  = ws + 896;
    float* st_u0_sc  = ws + 1536; float* st_u0_sh  = ws + 1600;
    float* st_u1_sc  = ws + 1664; float* st_u1_sh  = ws + 1728;
    float* st_f0_sc  = ws + 1792; float* st_f0_sh  = ws + 1856;
    float* st_f1_sc  = ws + 1920; float* st_f1_sh  = ws + 1984;

    float* fcat   = ws + OFF_FCAT;
    float* Wdt    = ws + OFF_WDT;     // written after fcat is dead
    float* dec_in = ws + OFF_DECIN;
    float* down   = ws + OFF_DOWN;
    float* dec_out= ws + OFF_DECOUT;
    float* uc0    = ws + OFF_UC0;
    float* uc1    = ws + OFF_UC1;
    float* tok    = ws + OFF_TOK;
    float* fus0   = ws + OFF_FUS0;
    float* fus1   = ws + OFF_FUS1;

    // 1. build concat input
    k_fcat<<<38400, 256, 0, stream>>>(features, high, fcat);
    // 2. BN stats on fcat (240 ch, 64x64, N=10)
    k_bn_stats<<<240, 256, 0, stream>>>(fcat, bn_in_g, bn_in_b, st_in_sc, st_in_sh, 240, 12, 10);
    // 3. down conv (affine fused on reads)
    k_down<<<15360, 256, 0, stream>>>(fcat, down_w, st_in_sc, st_in_sh, down);
    // 4. precompute combined dt matrix (fcat region now dead)
    k_wdt<<<192, 256, 0, stream>>>(m_dt_w, m_xproj_w, Wdt);
    // 5. BN stats on down (384 ch, 32x32, N=10)
    k_bn_stats<<<384, 256, 0, stream>>>(down, down_bn_g, down_bn_b, st_dn_sc, st_dn_sh, 384, 10, 10);
    // 6. in-place BN+SiLU
    k_affine_silu<<<15360, 256, 0, stream>>>(down, st_dn_sc, st_dn_sh, 384, 10, 3932160);
    // 7. emb conv -> token layout
    k_emb<<<30720, 256, 0, stream>>>(down, emb_w, emb_b, tok);
    // 8. fused mamba (LN1 + 3 chunks + LN2 + transpose)
    k_mamba2<<<10240, 128, 0, stream>>>(tok, m_in_w, m_conv_w, m_conv_b, m_xproj_w,
                                        Wdt, m_dt_b, m_A_log, m_D, m_out_w,
                                        ln1_g, ln1_b, ln2_g, ln2_b, dec_in);
    // 9. dec conv
    k_dec<<<5120, 256, 0, stream>>>(dec_in, dec_w, dec_b, dec_out);
    // 10. up 1x1 convs at 32x32
    k_up<<<5120, 256, 0, stream>>>(dec_out, up0_w, up1_w, uc0, uc1);
    // 11. BN stats + activate uc0/uc1 (stats on upsampled map == stats at 32x32)
    k_bn_stats<<<64, 256, 0, stream>>>(uc0, up0_bn_g, up0_bn_b, st_u0_sc, st_u0_sh, 64, 10, 10);
    k_bn_stats<<<64, 256, 0, stream>>>(uc1, up1_bn_g, up1_bn_b, st_u1_sc, st_u1_sh, 64, 10, 10);
    k_affine_silu<<<2560, 256, 0, stream>>>(uc0, st_u0_sc, st_u0_sh, 64, 10, 655360);
    k_affine_silu<<<2560, 256, 0, stream>>>(uc1, st_u1_sc, st_u1_sh, 64, 10, 655360);
    // 12. fuse convs
    k_fus<<<10240, 256, 0, stream>>>(uc0, fid0, fus0_w, fus0_b, fus0);
    k_fus<<<10240, 256, 0, stream>>>(uc1, fid1, fus1_w, fus1_b, fus1);
    // 13. BN stats + activate fus0/fus1
    k_bn_stats<<<64, 256, 0, stream>>>(fus0, fus0_bn_g, fus0_bn_b, st_f0_sc, st_f0_sh, 64, 12, 10);
    k_bn_stats<<<64, 256, 0, stream>>>(fus1, fus1_bn_g, fus1_bn_b, st_f1_sc, st_f1_sh, 64, 12, 10);
    k_affine_silu<<<10240, 256, 0, stream>>>(fus0, st_f0_sc, st_f0_sh, 64, 12, 2621440);
    k_affine_silu<<<10240, 256, 0, stream>>>(fus1, st_f1_sc, st_f1_sh, 64, 12, 2621440);
    // 14. final 1x1 + SiLU -> d_out
    k_final<<<10240, 256, 0, stream>>>(fus0, fus1, outf_w, outf_b, out);
}

// Round 4
// 7319.540 us; speedup vs baseline: 1.1402x; 1.1402x over previous
//
#include <hip/hip_runtime.h>
#include <math.h>

static __device__ __forceinline__ float silu_f(float x){ return x / (1.f + expf(-x)); }
static __device__ __forceinline__ float softplus_f(float x){ return (x > 20.f) ? x : log1pf(expf(x)); }

// ---------------- workspace layout (float offsets) ----------------
// stats region [0,8192)
#define OFF_WDT    8192u        /* 49,152 (3,128,128) — written after fcat is dead */
#define OFF_FCAT   8192u        /* 9,830,400  (10,240,64,64) */
#define OFF_DECIN  5251072u     /* 2,621,440 reuse fcat region (fcat dead) */
#define OFF_DOWN   9838592u     /* 3,932,160  (10,384,32,32) */
#define OFF_DECOUT 9838592u     /* 1,310,720  reuse down region */
#define OFF_UC0    11149312u    /* 655,360 */
#define OFF_UC1    11804672u    /* 655,360 */
#define OFF_TOK    13770752u    /* 7,864,320  (10240,12,64) */
#define OFF_FUS0   13770752u    /* 2,621,440  reuse tok region */
#define OFF_FUS1   16392192u    /* 2,621,440 */

// ---------------- K1: f = concat([high, features + tile(high,4)]) ----------------
__global__ __launch_bounds__(256) void k_fcat(const float* __restrict__ feat,
                                              const float* __restrict__ high,
                                              float* __restrict__ out){
    int idx = blockIdx.x*256 + threadIdx.x;          // total 9,830,400
    if (idx >= 9830400) return;
    int b   = idx / 983040;
    int rem = idx - b*983040;
    int c   = rem >> 12;
    int hw  = rem & 4095;
    float v;
    if (c < 48){
        v = high[((size_t)b*48 + c)*4096 + hw];
    } else {
        int c2 = c - 48;
        v = feat[((size_t)b*192 + c2)*4096 + hw] + high[((size_t)b*48 + (c2 % 48))*4096 + hw];
    }
    out[idx] = v;
}

// ---------------- generic BN stats: one block per channel ----------------
__global__ __launch_bounds__(256) void k_bn_stats(const float* __restrict__ x,
                                                  const float* __restrict__ g,
                                                  const float* __restrict__ b,
                                                  float* __restrict__ scale,
                                                  float* __restrict__ shift,
                                                  int C, int hwshift, int N){
    int c = blockIdx.x;
    int HW = 1 << hwshift;
    int total = N << hwshift;
    float s = 0.f, s2 = 0.f;
    for (int i = threadIdx.x; i < total; i += 256){
        int n  = i >> hwshift;
        int hw = i & (HW - 1);
        float v = x[((size_t)n*C + c)*HW + hw];
        s += v; s2 = fmaf(v, v, s2);
    }
    __shared__ float rs[256], rq[256];
    rs[threadIdx.x] = s; rq[threadIdx.x] = s2;
    __syncthreads();
    for (int off = 128; off; off >>= 1){
        if (threadIdx.x < off){ rs[threadIdx.x] += rs[threadIdx.x+off]; rq[threadIdx.x] += rq[threadIdx.x+off]; }
        __syncthreads();
    }
    if (threadIdx.x == 0){
        float inv = 1.f / (float)total;
        float m   = rs[0]*inv;
        float var = rq[0]*inv - m*m;
        if (var < 0.f) var = 0.f;
        float sc = g[c] * rsqrtf(var + 1e-5f);
        scale[c] = sc;
        shift[c] = b[c] - m*sc;
    }
}

// ---------------- in-place affine + SiLU ----------------
__global__ __launch_bounds__(256) void k_affine_silu(float* __restrict__ x,
                                                     const float* __restrict__ scale,
                                                     const float* __restrict__ shift,
                                                     int C, int hwshift, int total){
    int idx = blockIdx.x*256 + threadIdx.x;
    if (idx >= total) return;
    int c = (idx >> hwshift) % C;
    float v = fmaf(x[idx], scale[c], shift[c]);
    x[idx] = silu_f(v);
}

// ---------------- down conv: 3x3 s2 g12, BN(input) fused ----------------
__global__ __launch_bounds__(256) void k_down(const float* __restrict__ fcat,
                                              const float* __restrict__ w,
                                              const float* __restrict__ sc,
                                              const float* __restrict__ sh,
                                              float* __restrict__ out){
    int idx = blockIdx.x*256 + threadIdx.x;          // 3,932,160 = 10*384*1024
    if (idx >= 3932160) return;
    int b   = idx / 393216;
    int rem = idx - b*393216;
    int o   = rem >> 10;
    int hw  = rem & 1023;
    int oh = hw >> 5, ow = hw & 31;
    int ibase = (o >> 5) * 20;                        // group = o/32, 20 in-ch per group
    const float* wt = w + (size_t)o*180;              // 20*9
    float acc = 0.f;
    for (int ci = 0; ci < 20; ++ci){
        int c = ibase + ci;
        const float* inp = fcat + ((size_t)b*240 + c)*4096;
        float s = sc[c], t = sh[c];
        const float* wr = wt + ci*9;
        #pragma unroll
        for (int kh = 0; kh < 3; ++kh){
            int ih = oh*2 + kh - 1;
            if (ih < 0 || ih >= 64) continue;
            #pragma unroll
            for (int kw = 0; kw < 3; ++kw){
                int iw = ow*2 + kw - 1;
                if (iw < 0 || iw >= 64) continue;
                acc += fmaf(inp[ih*64 + iw], s, t) * wr[kh*3 + kw];
            }
        }
    }
    out[idx] = acc;
}

// ---------------- emb conv: 3x3 g12 + bias, writes token layout ----------------
__global__ __launch_bounds__(256) void k_emb(const float* __restrict__ down_act,
                                             const float* __restrict__ w,
                                             const float* __restrict__ bias,
                                             float* __restrict__ tok){
    int idx = blockIdx.x*256 + threadIdx.x;          // 7,864,320 = 10*768*1024
    if (idx >= 7864320) return;
    int b   = idx / 786432;
    int rem = idx - b*786432;
    int c   = rem >> 10;
    int hw  = rem & 1023;
    int oh = hw >> 5, ow = hw & 31;
    int ibase = (c >> 6) * 32;                        // group = c/64, 32 in-ch
    const float* wt = w + (size_t)c*288;              // 32*9
    float acc = bias[c];
    for (int ci = 0; ci < 32; ++ci){
        const float* inp = down_act + ((size_t)b*384 + ibase + ci)*1024;
        const float* wr = wt + ci*9;
        #pragma unroll
        for (int kh = 0; kh < 3; ++kh){
            int ih = oh + kh - 1;
            if (ih < 0 || ih >= 32) continue;
            #pragma unroll
            for (int kw = 0; kw < 3; ++kw){
                int iw = ow + kw - 1;
                if (iw < 0 || iw >= 32) continue;
                acc = fmaf(inp[ih*32 + iw], wr[kh*3 + kw], acc);
            }
        }
    }
    tok[((size_t)(b*1024 + hw))*768 + c] = acc;
}

// ---------------- wave-64 reductions ----------------
static __device__ __forceinline__ float wsum64(float v){
    #pragma unroll
    for (int m = 32; m; m >>= 1) v += __shfl_xor(v, m, 64);
    return v;
}

// ---------------- precompute W_dt[chunk][ch][d] = sum_r dt_w[chunk][ch][r]*xproj_w[chunk][r][d] ----------------
__global__ __launch_bounds__(256) void k_wdt(const float* __restrict__ dt_w,
                                             const float* __restrict__ xproj_w,
                                             float* __restrict__ Wdt){
    int idx = blockIdx.x*256 + threadIdx.x;          // 49,152
    if (idx >= 49152) return;
    int chunk = idx >> 14;
    int rem   = idx & 16383;
    int ch    = rem >> 7;
    int d     = rem & 127;
    const float* dwr = dt_w + (size_t)(chunk*128 + ch)*32;
    const float* xw  = xproj_w + (size_t)chunk*8192 + d;   // row r at r*128+d
    float acc = 0.f;
    #pragma unroll
    for (int r = 0; r < 32; ++r) acc = fmaf(dwr[r], xw[(size_t)r*128], acc);
    Wdt[idx] = acc;
}

// ---------------- fused mamba: LN1 + in-proj + dt/BC + scan + gate + out-proj + LN2 + transpose ----------------
// one block = one token, 128 threads = one channel each, state in registers,
// all cross-phase arrays in LDS (NO runtime-indexed register arrays -> no scratch)
// launch_bounds(128,2): VGPR budget 256 — do NOT cap tighter, 64-VGPR cap spilled 13 GB (R3)
__global__ __launch_bounds__(128, 2) void k_mamba2(const float* __restrict__ tok,  // [10240][768]
                                                const float* __restrict__ in_w,    // (3,256,64)
                                                const float* __restrict__ conv_w,  // (3,128)
                                                const float* __restrict__ conv_b,
                                                const float* __restrict__ xproj_w, // (3,64,128)
                                                const float* __restrict__ Wdt,     // (3,128,128)
                                                const float* __restrict__ dt_b,    // (3,128)
                                                const float* __restrict__ A_log,   // (3,128,16)
                                                const float* __restrict__ Dp,      // (3,128)
                                                const float* __restrict__ out_w,   // (3,64,128)
                                                const float* __restrict__ ln1_g,
                                                const float* __restrict__ ln1_b,
                                                const float* __restrict__ ln2_g,
                                                const float* __restrict__ ln2_b,
                                                float* __restrict__ dec_in){       // (10,256,1024)
    int token = blockIdx.x;
    int tid   = threadIdx.x;           // 0..127
    int lane  = tid & 63, wv = tid >> 6;
    int ch    = tid;

    __shared__ float xs[12][64];       // LN1'd tokens
    __shared__ float raw[4][64];       // pre-LN rows 8..11 (mfi)
    __shared__ float xi_s[12][128];
    __shared__ float dtv_s[12][128];   // dt values (LDS, conflict-free: same s, consecutive ch)
    __shared__ float bc[12][32];
    __shared__ float yz[4][128];

    // ---- load + LN1 (wave per row) ----
    const float* trow = tok + (size_t)token*768;
    for (int r = wv; r < 12; r += 2){
        float v = trow[r*64 + lane];
        if (r >= 8) raw[r-8][lane] = v;
        float m  = wsum64(v) * (1.f/64.f);
        float dv = v - m;
        float var = wsum64(dv*dv) * (1.f/64.f);
        xs[r][lane] = dv*rsqrtf(var + 1e-5f)*ln1_g[lane] + ln1_b[lane];
    }
    __syncthreads();

    // ---- in-proj (+conv scale + silu) for all 12 steps; z for steps 8..11 ----
    float zrow[4];
    for (int chunk = 0; chunk < 3; ++chunk){
        const float4* wr = (const float4*)(in_w + ((size_t)chunk*256 + ch)*64);
        float a0=0.f, a1=0.f, a2=0.f, a3=0.f;
        int s0 = chunk*4;
        #pragma unroll
        for (int j = 0; j < 16; ++j){
            float4 w = wr[j];
            int d = j*4;
            a0 = fmaf(xs[s0+0][d], w.x, a0); a0 = fmaf(xs[s0+0][d+1], w.y, a0);
            a0 = fmaf(xs[s0+0][d+2], w.z, a0); a0 = fmaf(xs[s0+0][d+3], w.w, a0);
            a1 = fmaf(xs[s0+1][d], w.x, a1); a1 = fmaf(xs[s0+1][d+1], w.y, a1);
            a1 = fmaf(xs[s0+1][d+2], w.z, a1); a1 = fmaf(xs[s0+1][d+3], w.w, a1);
            a2 = fmaf(xs[s0+2][d], w.x, a2); a2 = fmaf(xs[s0+2][d+1], w.y, a2);
            a2 = fmaf(xs[s0+2][d+2], w.z, a2); a2 = fmaf(xs[s0+2][d+3], w.w, a2);
            a3 = fmaf(xs[s0+3][d], w.x, a3); a3 = fmaf(xs[s0+3][d+1], w.y, a3);
            a3 = fmaf(xs[s0+3][d+2], w.z, a3); a3 = fmaf(xs[s0+3][d+3], w.w, a3);
        }
        float cw = conv_w[chunk*128 + ch], cb = conv_b[chunk*128 + ch];
        xi_s[s0+0][ch] = silu_f(fmaf(a0, cw, cb));
        xi_s[s0+1][ch] = silu_f(fmaf(a1, cw, cb));
        xi_s[s0+2][ch] = silu_f(fmaf(a2, cw, cb));
        xi_s[s0+3][ch] = silu_f(fmaf(a3, cw, cb));
    }
    {   // z (chunk 2 only, rows 128+ch)
        const float4* wr = (const float4*)(in_w + ((size_t)2*256 + 128 + ch)*64);
        float a0=0.f, a1=0.f, a2=0.f, a3=0.f;
        #pragma unroll
        for (int j = 0; j < 16; ++j){
            float4 w = wr[j];
            int d = j*4;
            a0 = fmaf(xs[8][d], w.x, a0); a0 = fmaf(xs[8][d+1], w.y, a0);
            a0 = fmaf(xs[8][d+2], w.z, a0); a0 = fmaf(xs[8][d+3], w.w, a0);
            a1 = fmaf(xs[9][d], w.x, a1); a1 = fmaf(xs[9][d+1], w.y, a1);
            a1 = fmaf(xs[9][d+2], w.z, a1); a1 = fmaf(xs[9][d+3], w.w, a1);
            a2 = fmaf(xs[10][d], w.x, a2); a2 = fmaf(xs[10][d+1], w.y, a2);
            a2 = fmaf(xs[10][d+2], w.z, a2); a2 = fmaf(xs[10][d+3], w.w, a2);
            a3 = fmaf(xs[11][d], w.x, a3); a3 = fmaf(xs[11][d+1], w.y, a3);
            a3 = fmaf(xs[11][d+2], w.z, a3); a3 = fmaf(xs[11][d+3], w.w, a3);
        }
        zrow[0] = silu_f(a0); zrow[1] = silu_f(a1); zrow[2] = silu_f(a2); zrow[3] = silu_f(a3);
    }
    __syncthreads();

    // ---- dt -> LDS (via combined W_dt) ----
    for (int chunk = 0; chunk < 3; ++chunk){
        const float4* wr = (const float4*)(Wdt + ((size_t)chunk*128 + ch)*128);
        float a0=0.f, a1=0.f, a2=0.f, a3=0.f;
        int s0 = chunk*4;
        #pragma unroll
        for (int j = 0; j < 32; ++j){
            float4 w = wr[j];
            int d = j*4;
            a0 = fmaf(xi_s[s0+0][d], w.x, a0); a0 = fmaf(xi_s[s0+0][d+1], w.y, a0);
            a0 = fmaf(xi_s[s0+0][d+2], w.z, a0); a0 = fmaf(xi_s[s0+0][d+3], w.w, a0);
            a1 = fmaf(xi_s[s0+1][d], w.x, a1); a1 = fmaf(xi_s[s0+1][d+1], w.y, a1);
            a1 = fmaf(xi_s[s0+1][d+2], w.z, a1); a1 = fmaf(xi_s[s0+1][d+3], w.w, a1);
            a2 = fmaf(xi_s[s0+2][d], w.x, a2); a2 = fmaf(xi_s[s0+2][d+1], w.y, a2);
            a2 = fmaf(xi_s[s0+2][d+2], w.z, a2); a2 = fmaf(xi_s[s0+2][d+3], w.w, a2);
            a3 = fmaf(xi_s[s0+3][d], w.x, a3); a3 = fmaf(xi_s[s0+3][d+1], w.y, a3);
            a3 = fmaf(xi_s[s0+3][d+2], w.z, a3); a3 = fmaf(xi_s[s0+3][d+3], w.w, a3);
        }
        float db = dt_b[chunk*128 + ch];
        dtv_s[s0+0][ch] = softplus_f(a0 + db);
        dtv_s[s0+1][ch] = softplus_f(a1 + db);
        dtv_s[s0+2][ch] = softplus_f(a2 + db);
        dtv_s[s0+3][ch] = softplus_f(a3 + db);
    }

    // ---- B and C (384 outputs, 3 per thread) ----
    for (int i = tid; i < 384; i += 128){
        int s = i >> 5, e = i & 31;
        int chunk = s >> 2;
        const float4* wr = (const float4*)(xproj_w + ((size_t)chunk*64 + 32 + e)*128);
        float acc = 0.f;
        #pragma unroll
        for (int j = 0; j < 32; ++j){
            float4 w = wr[j];
            int d = j*4;
            acc = fmaf(xi_s[s][d], w.x, acc); acc = fmaf(xi_s[s][d+1], w.y, acc);
            acc = fmaf(xi_s[s][d+2], w.z, acc); acc = fmaf(xi_s[s][d+3], w.w, acc);
        }
        bc[s][e] = acc;
    }
    __syncthreads();

    // ---- scan (state + A in registers, all static indices) ----
    float st[16];
    #pragma unroll
    for (int n = 0; n < 16; ++n) st[n] = 0.f;
    for (int chunk = 0; chunk < 3; ++chunk){
        float a[16];
        const float* ar = A_log + ((size_t)chunk*128 + ch)*16;
        #pragma unroll
        for (int n = 0; n < 16; ++n) a[n] = -expf(ar[n]);
        #pragma unroll
        for (int t = 0; t < 4; ++t){
            int s = chunk*4 + t;
            float dtc = dtv_s[s][ch];
            float xiv = xi_s[s][ch];
            float dx  = dtc * xiv;
            if (chunk < 2){
                #pragma unroll
                for (int n = 0; n < 16; ++n)
                    st[n] = fmaf(st[n], expf(dtc*a[n]), dx*bc[s][n]);
            } else {
                float y = 0.f;
                #pragma unroll
                for (int n = 0; n < 16; ++n){
                    st[n] = fmaf(st[n], expf(dtc*a[n]), dx*bc[s][n]);
                    y = fmaf(st[n], bc[s][16+n], y);
                }
                y = fmaf(Dp[2*128 + ch], xiv, y);
                yz[t][ch] = y * zrow[t];
            }
        }
    }
    __syncthreads();

    // ---- out-proj + LN2 + transposed store ----
    int b = token >> 10, hw = token & 1023;
    #pragma unroll
    for (int p = 0; p < 2; ++p){
        int l = wv*2 + p;
        const float4* wr = (const float4*)(out_w + ((size_t)2*64 + lane)*128);
        float acc = 0.f;
        #pragma unroll
        for (int j = 0; j < 32; ++j){
            float4 w = wr[j];
            int d = j*4;
            acc = fmaf(yz[l][d], w.x, acc); acc = fmaf(yz[l][d+1], w.y, acc);
            acc = fmaf(yz[l][d+2], w.z, acc); acc = fmaf(yz[l][d+3], w.w, acc);
        }
        float v = raw[l][lane] + acc;
        float m  = wsum64(v) * (1.f/64.f);
        float dv = v - m;
        float var = wsum64(dv*dv) * (1.f/64.f);
        float r = dv*rsqrtf(var + 1e-5f)*ln2_g[lane] + ln2_b[lane];
        dec_in[(size_t)b*262144 + (size_t)(l*64 + lane)*1024 + hw] = r;
    }
}

// ---------------- dec conv: 3x3 g4 + bias ----------------
__global__ __launch_bounds__(256) void k_dec(const float* __restrict__ dec_in,
                                             const float* __restrict__ w,
                                             const float* __restrict__ bias,
                                             float* __restrict__ out){
    int idx = blockIdx.x*256 + threadIdx.x;          // 1,310,720 = 10*128*1024
    if (idx >= 1310720) return;
    int b   = idx / 131072;
    int rem = idx - b*131072;
    int o   = rem >> 10;
    int hw  = rem & 1023;
    int oh = hw >> 5, ow = hw & 31;
    int ibase = (o >> 5) * 64;
    const float* wt = w + (size_t)o*576;             // 64*9
    float acc = bias[o];
    for (int ci = 0; ci < 64; ++ci){
        const float* inp = dec_in + ((size_t)b*256 + ibase + ci)*1024;
        const float* wr = wt + ci*9;
        #pragma unroll
        for (int kh = 0; kh < 3; ++kh){
            int ih = oh + kh - 1;
            if (ih < 0 || ih >= 32) continue;
            #pragma unroll
            for (int kw = 0; kw < 3; ++kw){
                int iw = ow + kw - 1;
                if (iw < 0 || iw >= 32) continue;
                acc = fmaf(inp[ih*32 + iw], wr[kh*3 + kw], acc);
            }
        }
    }
    out[idx] = acc;
}

// ---------------- up 1x1 convs (both branches), at 32x32 ----------------
__global__ __launch_bounds__(256) void k_up(const float* __restrict__ dec_out,
                                            const float* __restrict__ w0,
                                            const float* __restrict__ w1,
                                            float* __restrict__ uc0,
                                            float* __restrict__ uc1){
    int idx = blockIdx.x*256 + threadIdx.x;          // 1,310,720 = 2*10*64*1024
    if (idx >= 1310720) return;
    int r = idx >= 655360;
    int j = idx - r*655360;
    int b   = j / 65536;
    int rem = j - b*65536;
    int o   = rem >> 10;
    int hw  = rem & 1023;
    const float* w = r ? w1 : w0;
    const float* in = dec_out + (size_t)b*131072 + (size_t)(r*64)*1024 + hw;
    float acc = 0.f;
    #pragma unroll
    for (int i = 0; i < 64; ++i) acc = fmaf(in[(size_t)i*1024], w[o*64 + i], acc);
    (r ? uc1 : uc0)[j] = acc;
}

// ---------------- fuse conv: 3x3, input = [upsampled uc_act(64) ; fid(64)] ----------------
__global__ __launch_bounds__(256) void k_fus(const float* __restrict__ uc_act,
                                             const float* __restrict__ fid,
                                             const float* __restrict__ w,
                                             const float* __restrict__ bias,
                                             float* __restrict__ out){
    int idx = blockIdx.x*256 + threadIdx.x;          // 2,621,440 = 10*64*4096
    if (idx >= 2621440) return;
    int b   = idx >> 18;
    int rem = idx & 262143;
    int o   = rem >> 12;
    int hw  = rem & 4095;
    int oh = hw >> 6, ow = hw & 63;
    const float* wt = w + (size_t)o*1152;            // 128*9
    float acc = bias[o];
    for (int i = 0; i < 64; ++i){
        const float* up = uc_act + ((size_t)b*64 + i)*1024;
        const float* wr = wt + i*9;
        #pragma unroll
        for (int kh = 0; kh < 3; ++kh){
            int ih = oh + kh - 1;
            if (ih < 0 || ih >= 64) continue;
            const float* uprow = up + (ih >> 1)*32;
            #pragma unroll
            for (int kw = 0; kw < 3; ++kw){
                int iw = ow + kw - 1;
                if (iw < 0 || iw >= 64) continue;
                acc = fmaf(uprow[iw >> 1], wr[kh*3 + kw], acc);
            }
        }
    }
    for (int i = 0; i < 64; ++i){
        const float* fp = fid + ((size_t)b*64 + i)*4096;
        const float* wr = wt + (64 + i)*9;
        #pragma unroll
        for (int kh = 0; kh < 3; ++kh){
            int ih = oh + kh - 1;
            if (ih < 0 || ih >= 64) continue;
            #pragma unroll
            for (int kw = 0; kw < 3; ++kw){
                int iw = ow + kw - 1;
                if (iw < 0 || iw >= 64) continue;
                acc = fmaf(fp[ih*64 + iw], wr[kh*3 + kw], acc);
            }
        }
    }
    out[idx] = acc;
}

// ---------------- final 1x1 conv + SiLU ----------------
__global__ __launch_bounds__(256) void k_final(const float* __restrict__ f0,
                                               const float* __restrict__ f1,
                                               const float* __restrict__ w,
                                               const float* __restrict__ bias,
                                               float* __restrict__ out){
    int idx = blockIdx.x*256 + threadIdx.x;          // 2,621,440 = 10*64*4096
    if (idx >= 2621440) return;
    int b   = idx >> 18;
    int rem = idx & 262143;
    int o   = rem >> 12;
    int hw  = rem & 4095;
    const float* p0 = f0 + (size_t)b*262144 + hw;
    const float* p1 = f1 + (size_t)b*262144 + hw;
    const float* w0 = w + o*128;
    float acc = bias[o];
    #pragma unroll
    for (int i = 0; i < 64; ++i) acc = fmaf(p0[(size_t)i*4096], w0[i], acc);
    #pragma unroll
    for (int i = 0; i < 64; ++i) acc = fmaf(p1[(size_t)i*4096], w0[64 + i], acc);
    out[idx] = silu_f(acc);
}

extern "C" void kernel_launch(void* const* d_in, const int* in_sizes, int n_in,
                              void* d_out, int out_size, void* d_ws, size_t ws_size,
                              hipStream_t stream) {
    const float* features = (const float*)d_in[0];
    const float* high     = (const float*)d_in[1];
    const float* fid0     = (const float*)d_in[2];
    const float* fid1     = (const float*)d_in[3];
    const float* bn_in_g  = (const float*)d_in[4];
    const float* bn_in_b  = (const float*)d_in[5];
    const float* down_w   = (const float*)d_in[6];
    const float* down_bn_g= (const float*)d_in[7];
    const float* down_bn_b= (const float*)d_in[8];
    const float* emb_w    = (const float*)d_in[9];
    const float* emb_b    = (const float*)d_in[10];
    const float* ln1_g    = (const float*)d_in[11];
    const float* ln1_b    = (const float*)d_in[12];
    const float* m_in_w   = (const float*)d_in[13];
    const float* m_conv_w = (const float*)d_in[14];
    const float* m_conv_b = (const float*)d_in[15];
    const float* m_xproj_w= (const float*)d_in[16];
    const float* m_dt_w   = (const float*)d_in[17];
    const float* m_dt_b   = (const float*)d_in[18];
    const float* m_A_log  = (const float*)d_in[19];
    const float* m_D      = (const float*)d_in[20];
    const float* m_out_w  = (const float*)d_in[21];
    const float* ln2_g    = (const float*)d_in[22];
    const float* ln2_b    = (const float*)d_in[23];
    const float* dec_w    = (const float*)d_in[24];
    const float* dec_b    = (const float*)d_in[25];
    const float* up0_w    = (const float*)d_in[26];
    const float* up0_bn_g = (const float*)d_in[27];
    const float* up0_bn_b = (const float*)d_in[28];
    const float* up1_w    = (const float*)d_in[29];
    const float* up1_bn_g = (const float*)d_in[30];
    const float* up1_bn_b = (const float*)d_in[31];
    const float* fus0_w   = (const float*)d_in[32];
    const float* fus0_b   = (const float*)d_in[33];
    const float* fus0_bn_g= (const float*)d_in[34];
    const float* fus0_bn_b= (const float*)d_in[35];
    const float* fus1_w   = (const float*)d_in[36];
    const float* fus1_b   = (const float*)d_in[37];
    const float* fus1_bn_g= (const float*)d_in[38];
    const float* fus1_bn_b= (const float*)d_in[39];
    const float* outf_w   = (const float*)d_in[40];
    const float* outf_b   = (const float*)d_in[41];

    float* ws = (float*)d_ws;
    float* out = (float*)d_out;

    float* st_in_sc  = ws + 0;    float* st_in_sh  = ws + 256;
    float* st_dn_sc  = ws + 512;  float* st_dn_sh  = ws + 896;
    float* st_u0_sc  = ws + 1536; float* st_u0_sh  = ws + 1600;
    float* st_u1_sc  = ws + 1664; float* st_u1_sh  = ws + 1728;
    float* st_f0_sc  = ws + 1792; float* st_f0_sh  = ws + 1856;
    float* st_f1_sc  = ws + 1920; float* st_f1_sh  = ws + 1984;

    float* fcat   = ws + OFF_FCAT;
    float* Wdt    = ws + OFF_WDT;     // written after fcat is dead
    float* dec_in = ws + OFF_DECIN;
    float* down   = ws + OFF_DOWN;
    float* dec_out= ws + OFF_DECOUT;
    float* uc0    = ws + OFF_UC0;
    float* uc1    = ws + OFF_UC1;
    float* tok    = ws + OFF_TOK;
    float* fus0   = ws + OFF_FUS0;
    float* fus1   = ws + OFF_FUS1;

    // 1. build concat input
    k_fcat<<<38400, 256, 0, stream>>>(features, high, fcat);
    // 2. BN stats on fcat (240 ch, 64x64, N=10)
    k_bn_stats<<<240, 256, 0, stream>>>(fcat, bn_in_g, bn_in_b, st_in_sc, st_in_sh, 240, 12, 10);
    // 3. down conv (affine fused on reads)
    k_down<<<15360, 256, 0, stream>>>(fcat, down_w, st_in_sc, st_in_sh, down);
    // 4. precompute combined dt matrix (fcat region now dead)
    k_wdt<<<192, 256, 0, stream>>>(m_dt_w, m_xproj_w, Wdt);
    // 5. BN stats on down (384 ch, 32x32, N=10)
    k_bn_stats<<<384, 256, 0, stream>>>(down, down_bn_g, down_bn_b, st_dn_sc, st_dn_sh, 384, 10, 10);
    // 6. in-place BN+SiLU
    k_affine_silu<<<15360, 256, 0, stream>>>(down, st_dn_sc, st_dn_sh, 384, 10, 3932160);
    // 7. emb conv -> token layout
    k_emb<<<30720, 256, 0, stream>>>(down, emb_w, emb_b, tok);
    // 8. fused mamba (LN1 + 3 chunks + LN2 + transpose)
    k_mamba2<<<10240, 128, 0, stream>>>(tok, m_in_w, m_conv_w, m_conv_b, m_xproj_w,
                                        Wdt, m_dt_b, m_A_log, m_D, m_out_w,
                                        ln1_g, ln1_b, ln2_g, ln2_b, dec_in);
    // 9. dec conv
    k_dec<<<5120, 256, 0, stream>>>(dec_in, dec_w, dec_b, dec_out);
    // 10. up 1x1 convs at 32x32
    k_up<<<5120, 256, 0, stream>>>(dec_out, up0_w, up1_w, uc0, uc1);
    // 11. BN stats + activate uc0/uc1 (stats on upsampled map == stats at 32x32)
    k_bn_stats<<<64, 256, 0, stream>>>(uc0, up0_bn_g, up0_bn_b, st_u0_sc, st_u0_sh, 64, 10, 10);
    k_bn_stats<<<64, 256, 0, stream>>>(uc1, up1_bn_g, up1_bn_b, st_u1_sc, st_u1_sh, 64, 10, 10);
    k_affine_silu<<<2560, 256, 0, stream>>>(uc0, st_u0_sc, st_u0_sh, 64, 10, 655360);
    k_affine_silu<<<2560, 256, 0, stream>>>(uc1, st_u1_sc, st_u1_sh, 64, 10, 655360);
    // 12. fuse convs
    k_fus<<<10240, 256, 0, stream>>>(uc0, fid0, fus0_w, fus0_b, fus0);
    k_fus<<<10240, 256, 0, stream>>>(uc1, fid1, fus1_w, fus1_b, fus1);
    // 13. BN stats + activate fus0/fus1
    k_bn_stats<<<64, 256, 0, stream>>>(fus0, fus0_bn_g, fus0_bn_b, st_f0_sc, st_f0_sh, 64, 12, 10);
    k_bn_stats<<<64, 256, 0, stream>>>(fus1, fus1_bn_g, fus1_bn_b, st_f1_sc, st_f1_sh, 64, 12, 10);
    k_affine_silu<<<10240, 256, 0, stream>>>(fus0, st_f0_sc, st_f0_sh, 64, 12, 2621440);
    k_affine_silu<<<10240, 256, 0, stream>>>(fus1, st_f1_sc, st_f1_sh, 64, 12, 2621440);
    // 14. final 1x1 + SiLU -> d_out
    k_final<<<10240, 256, 0, stream>>>(fus0, fus1, outf_w, outf_b, out);
}

// Round 5
// 3701.909 us; speedup vs baseline: 2.2545x; 1.9772x over previous
//
#include <hip/hip_runtime.h>
#include <math.h>

static __device__ __forceinline__ float silu_f(float x){ return x / (1.f + expf(-x)); }
static __device__ __forceinline__ float softplus_f(float x){ return (x > 20.f) ? x : log1pf(expf(x)); }

// ---------------- workspace layout (float offsets) ----------------
// stats region [0,8192)
// transposed weights live in the (dead-after-k_down) fcat region:
#define OFF_INT    8192u        /* 49,152  inT  (3,64,256)  */
#define OFF_WDTT   57344u       /* 49,152  WdtT (3,128,128) */
#define OFF_BCT    106496u      /* 12,288  bcT  (3,128,32)  */
#define OFF_OUTT   118784u      /* 8,192   outT (128,64)    */
#define OFF_FCAT   8192u        /* 9,830,400  (10,240,64,64) */
#define OFF_DECIN  5251072u     /* 2,621,440 reuse fcat tail (fcat dead) */
#define OFF_DOWN   9838592u     /* 3,932,160  (10,384,32,32) */
#define OFF_DECOUT 9838592u     /* 1,310,720  reuse down region */
#define OFF_UC0    11149312u    /* 655,360 */
#define OFF_UC1    11804672u    /* 655,360 */
#define OFF_TOK    13770752u    /* 7,864,320  (10240,12,64) */
#define OFF_FUS0   13770752u    /* 2,621,440  reuse tok region */
#define OFF_FUS1   16392192u    /* 2,621,440 */

// ---------------- K1: f = concat([high, features + tile(high,4)]) ----------------
__global__ __launch_bounds__(256) void k_fcat(const float* __restrict__ feat,
                                              const float* __restrict__ high,
                                              float* __restrict__ out){
    int idx = blockIdx.x*256 + threadIdx.x;          // total 9,830,400
    if (idx >= 9830400) return;
    int b   = idx / 983040;
    int rem = idx - b*983040;
    int c   = rem >> 12;
    int hw  = rem & 4095;
    float v;
    if (c < 48){
        v = high[((size_t)b*48 + c)*4096 + hw];
    } else {
        int c2 = c - 48;
        v = feat[((size_t)b*192 + c2)*4096 + hw] + high[((size_t)b*48 + (c2 % 48))*4096 + hw];
    }
    out[idx] = v;
}

// ---------------- generic BN stats: one block per channel ----------------
__global__ __launch_bounds__(256) void k_bn_stats(const float* __restrict__ x,
                                                  const float* __restrict__ g,
                                                  const float* __restrict__ b,
                                                  float* __restrict__ scale,
                                                  float* __restrict__ shift,
                                                  int C, int hwshift, int N){
    int c = blockIdx.x;
    int HW = 1 << hwshift;
    int total = N << hwshift;
    float s = 0.f, s2 = 0.f;
    for (int i = threadIdx.x; i < total; i += 256){
        int n  = i >> hwshift;
        int hw = i & (HW - 1);
        float v = x[((size_t)n*C + c)*HW + hw];
        s += v; s2 = fmaf(v, v, s2);
    }
    __shared__ float rs[256], rq[256];
    rs[threadIdx.x] = s; rq[threadIdx.x] = s2;
    __syncthreads();
    for (int off = 128; off; off >>= 1){
        if (threadIdx.x < off){ rs[threadIdx.x] += rs[threadIdx.x+off]; rq[threadIdx.x] += rq[threadIdx.x+off]; }
        __syncthreads();
    }
    if (threadIdx.x == 0){
        float inv = 1.f / (float)total;
        float m   = rs[0]*inv;
        float var = rq[0]*inv - m*m;
        if (var < 0.f) var = 0.f;
        float sc = g[c] * rsqrtf(var + 1e-5f);
        scale[c] = sc;
        shift[c] = b[c] - m*sc;
    }
}

// ---------------- in-place affine + SiLU ----------------
__global__ __launch_bounds__(256) void k_affine_silu(float* __restrict__ x,
                                                     const float* __restrict__ scale,
                                                     const float* __restrict__ shift,
                                                     int C, int hwshift, int total){
    int idx = blockIdx.x*256 + threadIdx.x;
    if (idx >= total) return;
    int c = (idx >> hwshift) % C;
    float v = fmaf(x[idx], scale[c], shift[c]);
    x[idx] = silu_f(v);
}

// ---------------- down conv: 3x3 s2 g12, BN(input) fused, weights in LDS ----------------
__global__ __launch_bounds__(256) void k_down(const float* __restrict__ fcat,
                                              const float* __restrict__ w,
                                              const float* __restrict__ sc,
                                              const float* __restrict__ sh,
                                              float* __restrict__ out){
    int idx = blockIdx.x*256 + threadIdx.x;          // 3,932,160 = 10*384*1024 (exact grid)
    int b   = idx / 393216;
    int rem = idx - b*393216;
    int o   = rem >> 10;
    int hw  = rem & 1023;
    int oh = hw >> 5, ow = hw & 31;
    int ibase = (o >> 5) * 20;                        // group = o/32, 20 in-ch per group
    __shared__ float w_s[180], s_s[20], t_s[20];
    if (threadIdx.x < 180) w_s[threadIdx.x] = w[(size_t)o*180 + threadIdx.x];
    if (threadIdx.x >= 180 && threadIdx.x < 200){ int i = threadIdx.x - 180; s_s[i] = sc[ibase+i]; t_s[i] = sh[ibase+i]; }
    __syncthreads();
    float acc = 0.f;
    for (int ci = 0; ci < 20; ++ci){
        const float* inp = fcat + ((size_t)b*240 + ibase + ci)*4096;
        float s = s_s[ci], t = t_s[ci];
        const float* wr = w_s + ci*9;
        #pragma unroll
        for (int kh = 0; kh < 3; ++kh){
            int ih = oh*2 + kh - 1;
            if (ih < 0 || ih >= 64) continue;
            #pragma unroll
            for (int kw = 0; kw < 3; ++kw){
                int iw = ow*2 + kw - 1;
                if (iw < 0 || iw >= 64) continue;
                acc += fmaf(inp[ih*64 + iw], s, t) * wr[kh*3 + kw];
            }
        }
    }
    out[idx] = acc;
}

// ---------------- emb conv: 3x3 g12 + bias, weights in LDS, writes token layout ----------------
__global__ __launch_bounds__(256) void k_emb(const float* __restrict__ down_act,
                                             const float* __restrict__ w,
                                             const float* __restrict__ bias,
                                             float* __restrict__ tok){
    int idx = blockIdx.x*256 + threadIdx.x;          // 7,864,320 = 10*768*1024 (exact)
    int b   = idx / 786432;
    int rem = idx - b*786432;
    int c   = rem >> 10;
    int hw  = rem & 1023;
    int oh = hw >> 5, ow = hw & 31;
    int ibase = (c >> 6) * 32;                        // group = c/64, 32 in-ch
    __shared__ float w_s[288];
    for (int i = threadIdx.x; i < 288; i += 256) w_s[i] = w[(size_t)c*288 + i];
    __syncthreads();
    float acc = bias[c];
    for (int ci = 0; ci < 32; ++ci){
        const float* inp = down_act + ((size_t)b*384 + ibase + ci)*1024;
        const float* wr = w_s + ci*9;
        #pragma unroll
        for (int kh = 0; kh < 3; ++kh){
            int ih = oh + kh - 1;
            if (ih < 0 || ih >= 32) continue;
            #pragma unroll
            for (int kw = 0; kw < 3; ++kw){
                int iw = ow + kw - 1;
                if (iw < 0 || iw >= 32) continue;
                acc = fmaf(inp[ih*32 + iw], wr[kh*3 + kw], acc);
            }
        }
    }
    tok[((size_t)(b*1024 + hw))*768 + c] = acc;
}

// ---------------- wave-64 reductions ----------------
static __device__ __forceinline__ float wsum64(float v){
    #pragma unroll
    for (int m = 32; m; m >>= 1) v += __shfl_xor(v, m, 64);
    return v;
}

// ---------------- prep: transposed weight copies (coalesced GEMV layout) ----------------
// inT[(c*64+d)*256+e] = in_w[(c*256+e)*64+d]
// WdtT[(c*128+d)*128+ch] = sum_r dt_w[c,ch,r]*xproj_w[c,r,d]
// bcT[(c*128+d)*32+e] = xproj_w[(c*64+32+e)*128+d]
// outT[ch*64+e] = out_w[(2*64+e)*128+ch]
__global__ __launch_bounds__(256) void k_prep(const float* __restrict__ in_w,
                                              const float* __restrict__ dt_w,
                                              const float* __restrict__ xproj_w,
                                              const float* __restrict__ out_w,
                                              float* __restrict__ inT,
                                              float* __restrict__ WdtT,
                                              float* __restrict__ bcT,
                                              float* __restrict__ outT){
    int idx = blockIdx.x*256 + threadIdx.x;          // 118,784 total (exact)
    if (idx < 49152){
        int c = idx >> 14, rem = idx & 16383;
        int d = rem >> 8, e = rem & 255;
        inT[idx] = in_w[((size_t)(c*256 + e))*64 + d];
    } else if (idx < 98304){
        int j = idx - 49152;
        int c = j >> 14, rem = j & 16383;
        int d = rem >> 7, ch = rem & 127;
        const float* dwr = dt_w + (size_t)(c*128 + ch)*32;
        const float* xw  = xproj_w + (size_t)c*8192 + d;
        float acc = 0.f;
        #pragma unroll
        for (int r = 0; r < 32; ++r) acc = fmaf(dwr[r], xw[(size_t)r*128], acc);
        WdtT[j] = acc;
    } else if (idx < 110592){
        int j = idx - 98304;
        int c = j >> 12, rem = j & 4095;
        int d = rem >> 5, e = rem & 31;
        bcT[j] = xproj_w[((size_t)(c*64 + 32 + e))*128 + d];
    } else {
        int j = idx - 110592;                        // 8192
        int ch = j >> 6, e = j & 63;
        outT[j] = out_w[((size_t)(128 + e))*128 + ch];
    }
}

// ---------------- fused mamba v3: transposed-weight GEMVs, minimal registers ----------------
// one block = one token, 128 threads. All weight reads coalesced (thread = output ch).
__global__ __launch_bounds__(128) void k_mamba3(const float* __restrict__ tok,     // [10240][768]
                                                const float* __restrict__ inT,     // (3,64,256)
                                                const float* __restrict__ conv_w,  // (3,128)
                                                const float* __restrict__ conv_b,
                                                const float* __restrict__ WdtT,    // (3,128,128)
                                                const float* __restrict__ bcT,     // (3,128,32)
                                                const float* __restrict__ dt_b,    // (3,128)
                                                const float* __restrict__ A_log,   // (3,128,16)
                                                const float* __restrict__ Dp,      // (3,128)
                                                const float* __restrict__ outT,    // (128,64)
                                                const float* __restrict__ ln1_g,
                                                const float* __restrict__ ln1_b,
                                                const float* __restrict__ ln2_g,
                                                const float* __restrict__ ln2_b,
                                                float* __restrict__ dec_in){       // (10,256,1024)
    int token = blockIdx.x;
    int tid   = threadIdx.x;           // 0..127
    int lane  = tid & 63, wv = tid >> 6;
    int ch    = tid;

    __shared__ float xs[12][64];       // LN1'd tokens
    __shared__ float raw[4][64];       // pre-LN rows 8..11 (mfi)
    __shared__ float xi_s[12][128];
    __shared__ float bc[4][32];        // current chunk's B|C per step
    __shared__ float yz[4][128];

    // ---- load + LN1 (wave per row) ----
    const float* trow = tok + (size_t)token*768;
    for (int r = wv; r < 12; r += 2){
        float v = trow[r*64 + lane];
        if (r >= 8) raw[r-8][lane] = v;
        float m  = wsum64(v) * (1.f/64.f);
        float dv = v - m;
        float var = wsum64(dv*dv) * (1.f/64.f);
        xs[r][lane] = dv*rsqrtf(var + 1e-5f)*ln1_g[lane] + ln1_b[lane];
    }
    __syncthreads();

    // ---- in-proj (coalesced: w = inT[d][ch]) + conv-scale + silu ----
    for (int c = 0; c < 3; ++c){
        const float* wp = inT + (size_t)c*16384 + ch;
        float a0=0.f, a1=0.f, a2=0.f, a3=0.f;
        int s0 = c*4;
        #pragma unroll 4
        for (int d = 0; d < 64; ++d){
            float w = wp[(size_t)d*256];
            a0 = fmaf(xs[s0+0][d], w, a0);
            a1 = fmaf(xs[s0+1][d], w, a1);
            a2 = fmaf(xs[s0+2][d], w, a2);
            a3 = fmaf(xs[s0+3][d], w, a3);
        }
        float cw = conv_w[c*128 + ch], cb = conv_b[c*128 + ch];
        xi_s[s0+0][ch] = silu_f(fmaf(a0, cw, cb));
        xi_s[s0+1][ch] = silu_f(fmaf(a1, cw, cb));
        xi_s[s0+2][ch] = silu_f(fmaf(a2, cw, cb));
        xi_s[s0+3][ch] = silu_f(fmaf(a3, cw, cb));
    }
    // z (chunk 2, rows 128..255 -> e = 128+ch)
    float zr0=0.f, zr1=0.f, zr2=0.f, zr3=0.f;
    {
        const float* wp = inT + (size_t)2*16384 + 128 + ch;
        #pragma unroll 4
        for (int d = 0; d < 64; ++d){
            float w = wp[(size_t)d*256];
            zr0 = fmaf(xs[8][d],  w, zr0);
            zr1 = fmaf(xs[9][d],  w, zr1);
            zr2 = fmaf(xs[10][d], w, zr2);
            zr3 = fmaf(xs[11][d], w, zr3);
        }
        zr0 = silu_f(zr0); zr1 = silu_f(zr1); zr2 = silu_f(zr2); zr3 = silu_f(zr3);
    }
    __syncthreads();

    // ---- per-chunk: dt (regs), bc (LDS), scan ----
    int sidx = tid >> 5, be = tid & 31;
    float st[16];
    #pragma unroll
    for (int n = 0; n < 16; ++n) st[n] = 0.f;

    for (int c = 0; c < 3; ++c){
        int s0 = c*4;
        // dt: 4 accs over d<128, w = WdtT[c][d][ch] coalesced
        float dts[4];
        {
            const float* wp = WdtT + (size_t)c*16384 + ch;
            float a0=0.f, a1=0.f, a2=0.f, a3=0.f;
            #pragma unroll 4
            for (int d = 0; d < 128; ++d){
                float w = wp[(size_t)d*128];
                a0 = fmaf(xi_s[s0+0][d], w, a0);
                a1 = fmaf(xi_s[s0+1][d], w, a1);
                a2 = fmaf(xi_s[s0+2][d], w, a2);
                a3 = fmaf(xi_s[s0+3][d], w, a3);
            }
            float db = dt_b[c*128 + ch];
            dts[0] = softplus_f(a0 + db);
            dts[1] = softplus_f(a1 + db);
            dts[2] = softplus_f(a2 + db);
            dts[3] = softplus_f(a3 + db);
        }
        // bc: thread (sidx,be) computes step s0+sidx, output be (B:0..15, C:16..31)
        float bcacc = 0.f;
        {
            const float* wp = bcT + (size_t)c*4096 + be;
            #pragma unroll 4
            for (int d = 0; d < 128; ++d)
                bcacc = fmaf(xi_s[s0+sidx][d], wp[(size_t)d*32], bcacc);
        }
        __syncthreads();                 // previous scan done reading bc
        bc[sidx][be] = bcacc;
        __syncthreads();                 // bc visible

        // A for this chunk
        float a[16];
        const float* ar = A_log + ((size_t)c*128 + ch)*16;
        #pragma unroll
        for (int n = 0; n < 16; ++n) a[n] = -expf(ar[n]);
        float Dch = Dp[c*128 + ch];

        #pragma unroll
        for (int t = 0; t < 4; ++t){
            float dtc = dts[t];
            float xiv = xi_s[s0+t][ch];
            float dx  = dtc * xiv;
            if (c < 2){
                #pragma unroll
                for (int n = 0; n < 16; ++n)
                    st[n] = fmaf(st[n], expf(dtc*a[n]), dx*bc[t][n]);
            } else {
                float y = 0.f;
                #pragma unroll
                for (int n = 0; n < 16; ++n){
                    st[n] = fmaf(st[n], expf(dtc*a[n]), dx*bc[t][n]);
                    y = fmaf(st[n], bc[t][16+n], y);
                }
                y = fmaf(Dch, xiv, y);
                float zr = (t==0)?zr0:((t==1)?zr1:((t==2)?zr2:zr3));
                yz[t][ch] = y * zr;
            }
        }
    }
    __syncthreads();

    // ---- out-proj (coalesced outT) + LN2 + transposed store ----
    int b = token >> 10, hw = token & 1023;
    int e = tid & 63, l2 = tid >> 6;
    #pragma unroll
    for (int p = 0; p < 2; ++p){
        int l = l2 + p*2;
        const float* wp = outT + e;
        float acc = 0.f;
        #pragma unroll 4
        for (int k = 0; k < 128; ++k)
            acc = fmaf(yz[l][k], wp[(size_t)k*64], acc);
        float v = raw[l][e] + acc;
        float m  = wsum64(v) * (1.f/64.f);
        float dv = v - m;
        float var = wsum64(dv*dv) * (1.f/64.f);
        float r = dv*rsqrtf(var + 1e-5f)*ln2_g[e] + ln2_b[e];
        dec_in[(size_t)b*262144 + (size_t)(l*64 + e)*1024 + hw] = r;
    }
}

// ---------------- dec conv: 3x3 g4 + bias, weights in LDS ----------------
__global__ __launch_bounds__(256) void k_dec(const float* __restrict__ dec_in,
                                             const float* __restrict__ w,
                                             const float* __restrict__ bias,
                                             float* __restrict__ out){
    int idx = blockIdx.x*256 + threadIdx.x;          // 1,310,720 (exact)
    int b   = idx / 131072;
    int rem = idx - b*131072;
    int o   = rem >> 10;
    int hw  = rem & 1023;
    int oh = hw >> 5, ow = hw & 31;
    int ibase = (o >> 5) * 64;
    __shared__ float w_s[576];
    for (int i = threadIdx.x; i < 576; i += 256) w_s[i] = w[(size_t)o*576 + i];
    __syncthreads();
    float acc = bias[o];
    for (int ci = 0; ci < 64; ++ci){
        const float* inp = dec_in + ((size_t)b*256 + ibase + ci)*1024;
        const float* wr = w_s + ci*9;
        #pragma unroll
        for (int kh = 0; kh < 3; ++kh){
            int ih = oh + kh - 1;
            if (ih < 0 || ih >= 32) continue;
            #pragma unroll
            for (int kw = 0; kw < 3; ++kw){
                int iw = ow + kw - 1;
                if (iw < 0 || iw >= 32) continue;
                acc = fmaf(inp[ih*32 + iw], wr[kh*3 + kw], acc);
            }
        }
    }
    out[idx] = acc;
}

// ---------------- up 1x1 convs (both branches), at 32x32, weights in LDS ----------------
__global__ __launch_bounds__(256) void k_up(const float* __restrict__ dec_out,
                                            const float* __restrict__ w0,
                                            const float* __restrict__ w1,
                                            float* __restrict__ uc0,
                                            float* __restrict__ uc1){
    int idx = blockIdx.x*256 + threadIdx.x;          // 1,310,720 (exact)
    int r = idx >= 655360;
    int j = idx - r*655360;
    int b   = j / 65536;
    int rem = j - b*65536;
    int o   = rem >> 10;
    int hw  = rem & 1023;
    __shared__ float w_s[64];
    if (threadIdx.x < 64) w_s[threadIdx.x] = (r ? w1 : w0)[o*64 + threadIdx.x];
    __syncthreads();
    const float* in = dec_out + (size_t)b*131072 + (size_t)(r*64)*1024 + hw;
    float acc = 0.f;
    #pragma unroll 8
    for (int i = 0; i < 64; ++i) acc = fmaf(in[(size_t)i*1024], w_s[i], acc);
    (r ? uc1 : uc0)[j] = acc;
}

// ---------------- fuse conv: 3x3, input = [upsampled uc_act(64) ; fid(64)], weights in LDS ----------------
__global__ __launch_bounds__(256) void k_fus(const float* __restrict__ uc_act,
                                             const float* __restrict__ fid,
                                             const float* __restrict__ w,
                                             const float* __restrict__ bias,
                                             float* __restrict__ out){
    int idx = blockIdx.x*256 + threadIdx.x;          // 2,621,440 (exact)
    int b   = idx >> 18;
    int rem = idx & 262143;
    int o   = rem >> 12;
    int hw  = rem & 4095;
    int oh = hw >> 6, ow = hw & 63;
    __shared__ float w_s[1152];
    for (int i = threadIdx.x; i < 1152; i += 256) w_s[i] = w[(size_t)o*1152 + i];
    __syncthreads();
    float acc = bias[o];
    for (int i = 0; i < 64; ++i){
        const float* up = uc_act + ((size_t)b*64 + i)*1024;
        const float* wr = w_s + i*9;
        #pragma unroll
        for (int kh = 0; kh < 3; ++kh){
            int ih = oh + kh - 1;
            if (ih < 0 || ih >= 64) continue;
            const float* uprow = up + (ih >> 1)*32;
            #pragma unroll
            for (int kw = 0; kw < 3; ++kw){
                int iw = ow + kw - 1;
                if (iw < 0 || iw >= 64) continue;
                acc = fmaf(uprow[iw >> 1], wr[kh*3 + kw], acc);
            }
        }
    }
    for (int i = 0; i < 64; ++i){
        const float* fp = fid + ((size_t)b*64 + i)*4096;
        const float* wr = w_s + (64 + i)*9;
        #pragma unroll
        for (int kh = 0; kh < 3; ++kh){
            int ih = oh + kh - 1;
            if (ih < 0 || ih >= 64) continue;
            #pragma unroll
            for (int kw = 0; kw < 3; ++kw){
                int iw = ow + kw - 1;
                if (iw < 0 || iw >= 64) continue;
                acc = fmaf(fp[ih*64 + iw], wr[kh*3 + kw], acc);
            }
        }
    }
    out[idx] = acc;
}

// ---------------- final 1x1 conv + SiLU, weights in LDS ----------------
__global__ __launch_bounds__(256) void k_final(const float* __restrict__ f0,
                                               const float* __restrict__ f1,
                                               const float* __restrict__ w,
                                               const float* __restrict__ bias,
                                               float* __restrict__ out){
    int idx = blockIdx.x*256 + threadIdx.x;          // 2,621,440 (exact)
    int b   = idx >> 18;
    int rem = idx & 262143;
    int o   = rem >> 12;
    int hw  = rem & 4095;
    __shared__ float w_s[128];
    if (threadIdx.x < 128) w_s[threadIdx.x] = w[o*128 + threadIdx.x];
    __syncthreads();
    const float* p0 = f0 + (size_t)b*262144 + hw;
    const float* p1 = f1 + (size_t)b*262144 + hw;
    float acc = bias[o];
    #pragma unroll 8
    for (int i = 0; i < 64; ++i) acc = fmaf(p0[(size_t)i*4096], w_s[i], acc);
    #pragma unroll 8
    for (int i = 0; i < 64; ++i) acc = fmaf(p1[(size_t)i*4096], w_s[64 + i], acc);
    out[idx] = silu_f(acc);
}

extern "C" void kernel_launch(void* const* d_in, const int* in_sizes, int n_in,
                              void* d_out, int out_size, void* d_ws, size_t ws_size,
                              hipStream_t stream) {
    const float* features = (const float*)d_in[0];
    const float* high     = (const float*)d_in[1];
    const float* fid0     = (const float*)d_in[2];
    const float* fid1     = (const float*)d_in[3];
    const float* bn_in_g  = (const float*)d_in[4];
    const float* bn_in_b  = (const float*)d_in[5];
    const float* down_w   = (const float*)d_in[6];
    const float* down_bn_g= (const float*)d_in[7];
    const float* down_bn_b= (const float*)d_in[8];
    const float* emb_w    = (const float*)d_in[9];
    const float* emb_b    = (const float*)d_in[10];
    const float* ln1_g    = (const float*)d_in[11];
    const float* ln1_b    = (const float*)d_in[12];
    const float* m_in_w   = (const float*)d_in[13];
    const float* m_conv_w = (const float*)d_in[14];
    const float* m_conv_b = (const float*)d_in[15];
    const float* m_xproj_w= (const float*)d_in[16];
    const float* m_dt_w   = (const float*)d_in[17];
    const float* m_dt_b   = (const float*)d_in[18];
    const float* m_A_log  = (const float*)d_in[19];
    const float* m_D      = (const float*)d_in[20];
    const float* m_out_w  = (const float*)d_in[21];
    const float* ln2_g    = (const float*)d_in[22];
    const float* ln2_b    = (const float*)d_in[23];
    const float* dec_w    = (const float*)d_in[24];
    const float* dec_b    = (const float*)d_in[25];
    const float* up0_w    = (const float*)d_in[26];
    const float* up0_bn_g = (const float*)d_in[27];
    const float* up0_bn_b = (const float*)d_in[28];
    const float* up1_w    = (const float*)d_in[29];
    const float* up1_bn_g = (const float*)d_in[30];
    const float* up1_bn_b = (const float*)d_in[31];
    const float* fus0_w   = (const float*)d_in[32];
    const float* fus0_b   = (const float*)d_in[33];
    const float* fus0_bn_g= (const float*)d_in[34];
    const float* fus0_bn_b= (const float*)d_in[35];
    const float* fus1_w   = (const float*)d_in[36];
    const float* fus1_b   = (const float*)d_in[37];
    const float* fus1_bn_g= (const float*)d_in[38];
    const float* fus1_bn_b= (const float*)d_in[39];
    const float* outf_w   = (const float*)d_in[40];
    const float* outf_b   = (const float*)d_in[41];

    float* ws = (float*)d_ws;
    float* out = (float*)d_out;

    float* st_in_sc  = ws + 0;    float* st_in_sh  = ws + 256;
    float* st_dn_sc  = ws + 512;  float* st_dn_sh  = ws + 896;
    float* st_u0_sc  = ws + 1536; float* st_u0_sh  = ws + 1600;
    float* st_u1_sc  = ws + 1664; float* st_u1_sh  = ws + 1728;
    float* st_f0_sc  = ws + 1792; float* st_f0_sh  = ws + 1856;
    float* st_f1_sc  = ws + 1920; float* st_f1_sh  = ws + 1984;

    float* fcat   = ws + OFF_FCAT;
    float* inT    = ws + OFF_INT;     // written after fcat is dead
    float* WdtT   = ws + OFF_WDTT;
    float* bcT    = ws + OFF_BCT;
    float* outT   = ws + OFF_OUTT;
    float* dec_in = ws + OFF_DECIN;
    float* down   = ws + OFF_DOWN;
    float* dec_out= ws + OFF_DECOUT;
    float* uc0    = ws + OFF_UC0;
    float* uc1    = ws + OFF_UC1;
    float* tok    = ws + OFF_TOK;
    float* fus0   = ws + OFF_FUS0;
    float* fus1   = ws + OFF_FUS1;

    // 1. build concat input
    k_fcat<<<38400, 256, 0, stream>>>(features, high, fcat);
    // 2. BN stats on fcat (240 ch, 64x64, N=10)
    k_bn_stats<<<240, 256, 0, stream>>>(fcat, bn_in_g, bn_in_b, st_in_sc, st_in_sh, 240, 12, 10);
    // 3. down conv (affine fused on reads)
    k_down<<<15360, 256, 0, stream>>>(fcat, down_w, st_in_sc, st_in_sh, down);
    // 4. transposed weight prep (fcat region now dead)
    k_prep<<<464, 256, 0, stream>>>(m_in_w, m_dt_w, m_xproj_w, m_out_w, inT, WdtT, bcT, outT);
    // 5. BN stats on down (384 ch, 32x32, N=10)
    k_bn_stats<<<384, 256, 0, stream>>>(down, down_bn_g, down_bn_b, st_dn_sc, st_dn_sh, 384, 10, 10);
    // 6. in-place BN+SiLU
    k_affine_silu<<<15360, 256, 0, stream>>>(down, st_dn_sc, st_dn_sh, 384, 10, 3932160);
    // 7. emb conv -> token layout
    k_emb<<<30720, 256, 0, stream>>>(down, emb_w, emb_b, tok);
    // 8. fused mamba v3
    k_mamba3<<<10240, 128, 0, stream>>>(tok, inT, m_conv_w, m_conv_b, WdtT, bcT,
                                        m_dt_b, m_A_log, m_D, outT,
                                        ln1_g, ln1_b, ln2_g, ln2_b, dec_in);
    // 9. dec conv
    k_dec<<<5120, 256, 0, stream>>>(dec_in, dec_w, dec_b, dec_out);
    // 10. up 1x1 convs at 32x32
    k_up<<<5120, 256, 0, stream>>>(dec_out, up0_w, up1_w, uc0, uc1);
    // 11. BN stats + activate uc0/uc1 (stats on upsampled map == stats at 32x32)
    k_bn_stats<<<64, 256, 0, stream>>>(uc0, up0_bn_g, up0_bn_b, st_u0_sc, st_u0_sh, 64, 10, 10);
    k_bn_stats<<<64, 256, 0, stream>>>(uc1, up1_bn_g, up1_bn_b, st_u1_sc, st_u1_sh, 64, 10, 10);
    k_affine_silu<<<2560, 256, 0, stream>>>(uc0, st_u0_sc, st_u0_sh, 64, 10, 655360);
    k_affine_silu<<<2560, 256, 0, stream>>>(uc1, st_u1_sc, st_u1_sh, 64, 10, 655360);
    // 12. fuse convs
    k_fus<<<10240, 256, 0, stream>>>(uc0, fid0, fus0_w, fus0_b, fus0);
    k_fus<<<10240, 256, 0, stream>>>(uc1, fid1, fus1_w, fus1_b, fus1);
    // 13. BN stats + activate fus0/fus1
    k_bn_stats<<<64, 256, 0, stream>>>(fus0, fus0_bn_g, fus0_bn_b, st_f0_sc, st_f0_sh, 64, 12, 10);
    k_bn_stats<<<64, 256, 0, stream>>>(fus1, fus1_bn_g, fus1_bn_b, st_f1_sc, st_f1_sh, 64, 12, 10);
    k_affine_silu<<<10240, 256, 0, stream>>>(fus0, st_f0_sc, st_f0_sh, 64, 12, 2621440);
    k_affine_silu<<<10240, 256, 0, stream>>>(fus1, st_f1_sc, st_f1_sh, 64, 12, 2621440);
    // 14. final 1x1 + SiLU -> d_out
    k_final<<<10240, 256, 0, stream>>>(fus0, fus1, outf_w, outf_b, out);
}

// Round 6
// 2532.606 us; speedup vs baseline: 3.2954x; 1.4617x over previous
//
#include <hip/hip_runtime.h>
#include <math.h>

static __device__ __forceinline__ float silu_f(float x){ return x / (1.f + expf(-x)); }
static __device__ __forceinline__ float softplus_f(float x){ return (x > 20.f) ? x : log1pf(expf(x)); }

// ---------------- workspace layout (float offsets) ----------------
// stats region [0,8192)
// transposed weights live in the (dead-after-k_down) fcat region:
#define OFF_INT    8192u        /* 49,152  inT  (3,64,256)  */
#define OFF_WDTT   57344u       /* 49,152  WdtT (3,128,128) */
#define OFF_BCT    106496u      /* 12,288  bcT  (3,128,32)  */
#define OFF_OUTT   118784u      /* 8,192   outT (128,64)    */
#define OFF_FCAT   8192u        /* 9,830,400  (10,240,64,64) */
#define OFF_DECIN  5251072u     /* 2,621,440 reuse fcat tail (fcat dead) */
#define OFF_DOWN   9838592u     /* 3,932,160  (10,384,32,32) */
#define OFF_DECOUT 9838592u     /* 1,310,720  reuse down region */
#define OFF_UC0    11149312u    /* 655,360 */
#define OFF_UC1    11804672u    /* 655,360 */
#define OFF_TOK    13770752u    /* 7,864,320  (10240,12,64) */
#define OFF_FUS0   13770752u    /* 2,621,440  reuse tok region */
#define OFF_FUS1   16392192u    /* 2,621,440 */

// ---------------- K1: f = concat([high, features + tile(high,4)]) ----------------
__global__ __launch_bounds__(256) void k_fcat(const float* __restrict__ feat,
                                              const float* __restrict__ high,
                                              float* __restrict__ out){
    int idx = blockIdx.x*256 + threadIdx.x;          // total 9,830,400
    if (idx >= 9830400) return;
    int b   = idx / 983040;
    int rem = idx - b*983040;
    int c   = rem >> 12;
    int hw  = rem & 4095;
    float v;
    if (c < 48){
        v = high[((size_t)b*48 + c)*4096 + hw];
    } else {
        int c2 = c - 48;
        v = feat[((size_t)b*192 + c2)*4096 + hw] + high[((size_t)b*48 + (c2 % 48))*4096 + hw];
    }
    out[idx] = v;
}

// ---------------- generic BN stats: one block per channel ----------------
__global__ __launch_bounds__(256) void k_bn_stats(const float* __restrict__ x,
                                                  const float* __restrict__ g,
                                                  const float* __restrict__ b,
                                                  float* __restrict__ scale,
                                                  float* __restrict__ shift,
                                                  int C, int hwshift, int N){
    int c = blockIdx.x;
    int HW = 1 << hwshift;
    int total = N << hwshift;
    float s = 0.f, s2 = 0.f;
    for (int i = threadIdx.x; i < total; i += 256){
        int n  = i >> hwshift;
        int hw = i & (HW - 1);
        float v = x[((size_t)n*C + c)*HW + hw];
        s += v; s2 = fmaf(v, v, s2);
    }
    __shared__ float rs[256], rq[256];
    rs[threadIdx.x] = s; rq[threadIdx.x] = s2;
    __syncthreads();
    for (int off = 128; off; off >>= 1){
        if (threadIdx.x < off){ rs[threadIdx.x] += rs[threadIdx.x+off]; rq[threadIdx.x] += rq[threadIdx.x+off]; }
        __syncthreads();
    }
    if (threadIdx.x == 0){
        float inv = 1.f / (float)total;
        float m   = rs[0]*inv;
        float var = rq[0]*inv - m*m;
        if (var < 0.f) var = 0.f;
        float sc = g[c] * rsqrtf(var + 1e-5f);
        scale[c] = sc;
        shift[c] = b[c] - m*sc;
    }
}

// ---------------- in-place affine + SiLU ----------------
__global__ __launch_bounds__(256) void k_affine_silu(float* __restrict__ x,
                                                     const float* __restrict__ scale,
                                                     const float* __restrict__ shift,
                                                     int C, int hwshift, int total){
    int idx = blockIdx.x*256 + threadIdx.x;
    if (idx >= total) return;
    int c = (idx >> hwshift) % C;
    float v = fmaf(x[idx], scale[c], shift[c]);
    x[idx] = silu_f(v);
}

// ---------------- down conv: 3x3 s2 g12, BN(input) fused, weights in LDS ----------------
__global__ __launch_bounds__(256) void k_down(const float* __restrict__ fcat,
                                              const float* __restrict__ w,
                                              const float* __restrict__ sc,
                                              const float* __restrict__ sh,
                                              float* __restrict__ out){
    int idx = blockIdx.x*256 + threadIdx.x;          // 3,932,160 = 10*384*1024 (exact grid)
    int b   = idx / 393216;
    int rem = idx - b*393216;
    int o   = rem >> 10;
    int hw  = rem & 1023;
    int oh = hw >> 5, ow = hw & 31;
    int ibase = (o >> 5) * 20;                        // group = o/32, 20 in-ch per group
    __shared__ float w_s[180], s_s[20], t_s[20];
    if (threadIdx.x < 180) w_s[threadIdx.x] = w[(size_t)o*180 + threadIdx.x];
    if (threadIdx.x >= 180 && threadIdx.x < 200){ int i = threadIdx.x - 180; s_s[i] = sc[ibase+i]; t_s[i] = sh[ibase+i]; }
    __syncthreads();
    float acc = 0.f;
    for (int ci = 0; ci < 20; ++ci){
        const float* inp = fcat + ((size_t)b*240 + ibase + ci)*4096;
        float s = s_s[ci], t = t_s[ci];
        const float* wr = w_s + ci*9;
        #pragma unroll
        for (int kh = 0; kh < 3; ++kh){
            int ih = oh*2 + kh - 1;
            if (ih < 0 || ih >= 64) continue;
            #pragma unroll
            for (int kw = 0; kw < 3; ++kw){
                int iw = ow*2 + kw - 1;
                if (iw < 0 || iw >= 64) continue;
                acc += fmaf(inp[ih*64 + iw], s, t) * wr[kh*3 + kw];
            }
        }
    }
    out[idx] = acc;
}

// ---------------- emb conv: 3x3 g12 + bias, weights in LDS, writes token layout ----------------
__global__ __launch_bounds__(256) void k_emb(const float* __restrict__ down_act,
                                             const float* __restrict__ w,
                                             const float* __restrict__ bias,
                                             float* __restrict__ tok){
    int idx = blockIdx.x*256 + threadIdx.x;          // 7,864,320 = 10*768*1024 (exact)
    int b   = idx / 786432;
    int rem = idx - b*786432;
    int c   = rem >> 10;
    int hw  = rem & 1023;
    int oh = hw >> 5, ow = hw & 31;
    int ibase = (c >> 6) * 32;                        // group = c/64, 32 in-ch
    __shared__ float w_s[288];
    for (int i = threadIdx.x; i < 288; i += 256) w_s[i] = w[(size_t)c*288 + i];
    __syncthreads();
    float acc = bias[c];
    for (int ci = 0; ci < 32; ++ci){
        const float* inp = down_act + ((size_t)b*384 + ibase + ci)*1024;
        const float* wr = w_s + ci*9;
        #pragma unroll
        for (int kh = 0; kh < 3; ++kh){
            int ih = oh + kh - 1;
            if (ih < 0 || ih >= 32) continue;
            #pragma unroll
            for (int kw = 0; kw < 3; ++kw){
                int iw = ow + kw - 1;
                if (iw < 0 || iw >= 32) continue;
                acc = fmaf(inp[ih*32 + iw], wr[kh*3 + kw], acc);
            }
        }
    }
    tok[((size_t)(b*1024 + hw))*768 + c] = acc;
}

// ---------------- wave-64 reductions ----------------
static __device__ __forceinline__ float wsum64(float v){
    #pragma unroll
    for (int m = 32; m; m >>= 1) v += __shfl_xor(v, m, 64);
    return v;
}

// ---------------- prep: transposed weight copies (coalesced GEMV layout) ----------------
__global__ __launch_bounds__(256) void k_prep(const float* __restrict__ in_w,
                                              const float* __restrict__ dt_w,
                                              const float* __restrict__ xproj_w,
                                              const float* __restrict__ out_w,
                                              float* __restrict__ inT,
                                              float* __restrict__ WdtT,
                                              float* __restrict__ bcT,
                                              float* __restrict__ outT){
    int idx = blockIdx.x*256 + threadIdx.x;          // 118,784 total (exact)
    if (idx < 49152){
        int c = idx >> 14, rem = idx & 16383;
        int d = rem >> 8, e = rem & 255;
        inT[idx] = in_w[((size_t)(c*256 + e))*64 + d];
    } else if (idx < 98304){
        int j = idx - 49152;
        int c = j >> 14, rem = j & 16383;
        int d = rem >> 7, ch = rem & 127;
        const float* dwr = dt_w + (size_t)(c*128 + ch)*32;
        const float* xw  = xproj_w + (size_t)c*8192 + d;
        float acc = 0.f;
        #pragma unroll
        for (int r = 0; r < 32; ++r) acc = fmaf(dwr[r], xw[(size_t)r*128], acc);
        WdtT[j] = acc;
    } else if (idx < 110592){
        int j = idx - 98304;
        int c = j >> 12, rem = j & 4095;
        int d = rem >> 5, e = rem & 31;
        bcT[j] = xproj_w[((size_t)(c*64 + 32 + e))*128 + d];
    } else {
        int j = idx - 110592;                        // 8192
        int ch = j >> 6, e = j & 63;
        outT[j] = out_w[((size_t)(128 + e))*128 + ch];
    }
}

// ---------------- fused mamba v3: transposed-weight GEMVs, minimal registers ----------------
__global__ __launch_bounds__(128) void k_mamba3(const float* __restrict__ tok,     // [10240][768]
                                                const float* __restrict__ inT,     // (3,64,256)
                                                const float* __restrict__ conv_w,  // (3,128)
                                                const float* __restrict__ conv_b,
                                                const float* __restrict__ WdtT,    // (3,128,128)
                                                const float* __restrict__ bcT,     // (3,128,32)
                                                const float* __restrict__ dt_b,    // (3,128)
                                                const float* __restrict__ A_log,   // (3,128,16)
                                                const float* __restrict__ Dp,      // (3,128)
                                                const float* __restrict__ outT,    // (128,64)
                                                const float* __restrict__ ln1_g,
                                                const float* __restrict__ ln1_b,
                                                const float* __restrict__ ln2_g,
                                                const float* __restrict__ ln2_b,
                                                float* __restrict__ dec_in){       // (10,256,1024)
    int token = blockIdx.x;
    int tid   = threadIdx.x;           // 0..127
    int lane  = tid & 63, wv = tid >> 6;
    int ch    = tid;

    __shared__ float xs[12][64];       // LN1'd tokens
    __shared__ float raw[4][64];       // pre-LN rows 8..11 (mfi)
    __shared__ float xi_s[12][128];
    __shared__ float bc[4][32];        // current chunk's B|C per step
    __shared__ float yz[4][128];

    // ---- load + LN1 (wave per row) ----
    const float* trow = tok + (size_t)token*768;
    for (int r = wv; r < 12; r += 2){
        float v = trow[r*64 + lane];
        if (r >= 8) raw[r-8][lane] = v;
        float m  = wsum64(v) * (1.f/64.f);
        float dv = v - m;
        float var = wsum64(dv*dv) * (1.f/64.f);
        xs[r][lane] = dv*rsqrtf(var + 1e-5f)*ln1_g[lane] + ln1_b[lane];
    }
    __syncthreads();

    // ---- in-proj (coalesced: w = inT[d][ch]) + conv-scale + silu ----
    for (int c = 0; c < 3; ++c){
        const float* wp = inT + (size_t)c*16384 + ch;
        float a0=0.f, a1=0.f, a2=0.f, a3=0.f;
        int s0 = c*4;
        #pragma unroll 4
        for (int d = 0; d < 64; ++d){
            float w = wp[(size_t)d*256];
            a0 = fmaf(xs[s0+0][d], w, a0);
            a1 = fmaf(xs[s0+1][d], w, a1);
            a2 = fmaf(xs[s0+2][d], w, a2);
            a3 = fmaf(xs[s0+3][d], w, a3);
        }
        float cw = conv_w[c*128 + ch], cb = conv_b[c*128 + ch];
        xi_s[s0+0][ch] = silu_f(fmaf(a0, cw, cb));
        xi_s[s0+1][ch] = silu_f(fmaf(a1, cw, cb));
        xi_s[s0+2][ch] = silu_f(fmaf(a2, cw, cb));
        xi_s[s0+3][ch] = silu_f(fmaf(a3, cw, cb));
    }
    // z (chunk 2, rows 128..255 -> e = 128+ch)
    float zr0=0.f, zr1=0.f, zr2=0.f, zr3=0.f;
    {
        const float* wp = inT + (size_t)2*16384 + 128 + ch;
        #pragma unroll 4
        for (int d = 0; d < 64; ++d){
            float w = wp[(size_t)d*256];
            zr0 = fmaf(xs[8][d],  w, zr0);
            zr1 = fmaf(xs[9][d],  w, zr1);
            zr2 = fmaf(xs[10][d], w, zr2);
            zr3 = fmaf(xs[11][d], w, zr3);
        }
        zr0 = silu_f(zr0); zr1 = silu_f(zr1); zr2 = silu_f(zr2); zr3 = silu_f(zr3);
    }
    __syncthreads();

    // ---- per-chunk: dt (regs), bc (LDS), scan ----
    int sidx = tid >> 5, be = tid & 31;
    float st[16];
    #pragma unroll
    for (int n = 0; n < 16; ++n) st[n] = 0.f;

    for (int c = 0; c < 3; ++c){
        int s0 = c*4;
        float dts[4];
        {
            const float* wp = WdtT + (size_t)c*16384 + ch;
            float a0=0.f, a1=0.f, a2=0.f, a3=0.f;
            #pragma unroll 4
            for (int d = 0; d < 128; ++d){
                float w = wp[(size_t)d*128];
                a0 = fmaf(xi_s[s0+0][d], w, a0);
                a1 = fmaf(xi_s[s0+1][d], w, a1);
                a2 = fmaf(xi_s[s0+2][d], w, a2);
                a3 = fmaf(xi_s[s0+3][d], w, a3);
            }
            float db = dt_b[c*128 + ch];
            dts[0] = softplus_f(a0 + db);
            dts[1] = softplus_f(a1 + db);
            dts[2] = softplus_f(a2 + db);
            dts[3] = softplus_f(a3 + db);
        }
        float bcacc = 0.f;
        {
            const float* wp = bcT + (size_t)c*4096 + be;
            #pragma unroll 4
            for (int d = 0; d < 128; ++d)
                bcacc = fmaf(xi_s[s0+sidx][d], wp[(size_t)d*32], bcacc);
        }
        __syncthreads();                 // previous scan done reading bc
        bc[sidx][be] = bcacc;
        __syncthreads();                 // bc visible

        float a[16];
        const float* ar = A_log + ((size_t)c*128 + ch)*16;
        #pragma unroll
        for (int n = 0; n < 16; ++n) a[n] = -expf(ar[n]);
        float Dch = Dp[c*128 + ch];

        #pragma unroll
        for (int t = 0; t < 4; ++t){
            float dtc = dts[t];
            float xiv = xi_s[s0+t][ch];
            float dx  = dtc * xiv;
            if (c < 2){
                #pragma unroll
                for (int n = 0; n < 16; ++n)
                    st[n] = fmaf(st[n], expf(dtc*a[n]), dx*bc[t][n]);
            } else {
                float y = 0.f;
                #pragma unroll
                for (int n = 0; n < 16; ++n){
                    st[n] = fmaf(st[n], expf(dtc*a[n]), dx*bc[t][n]);
                    y = fmaf(st[n], bc[t][16+n], y);
                }
                y = fmaf(Dch, xiv, y);
                float zr = (t==0)?zr0:((t==1)?zr1:((t==2)?zr2:zr3));
                yz[t][ch] = y * zr;
            }
        }
    }
    __syncthreads();

    // ---- out-proj (coalesced outT) + LN2 + transposed store ----
    int b = token >> 10, hw = token & 1023;
    int e = tid & 63, l2 = tid >> 6;
    #pragma unroll
    for (int p = 0; p < 2; ++p){
        int l = l2 + p*2;
        const float* wp = outT + e;
        float acc = 0.f;
        #pragma unroll 4
        for (int k = 0; k < 128; ++k)
            acc = fmaf(yz[l][k], wp[(size_t)k*64], acc);
        float v = raw[l][e] + acc;
        float m  = wsum64(v) * (1.f/64.f);
        float dv = v - m;
        float var = wsum64(dv*dv) * (1.f/64.f);
        float r = dv*rsqrtf(var + 1e-5f)*ln2_g[e] + ln2_b[e];
        dec_in[(size_t)b*262144 + (size_t)(l*64 + e)*1024 + hw] = r;
    }
}

// ---------------- dec conv: 3x3 g4 + bias, weights in LDS ----------------
__global__ __launch_bounds__(256) void k_dec(const float* __restrict__ dec_in,
                                             const float* __restrict__ w,
                                             const float* __restrict__ bias,
                                             float* __restrict__ out){
    int idx = blockIdx.x*256 + threadIdx.x;          // 1,310,720 (exact)
    int b   = idx / 131072;
    int rem = idx - b*131072;
    int o   = rem >> 10;
    int hw  = rem & 1023;
    int oh = hw >> 5, ow = hw & 31;
    int ibase = (o >> 5) * 64;
    __shared__ float w_s[576];
    for (int i = threadIdx.x; i < 576; i += 256) w_s[i] = w[(size_t)o*576 + i];
    __syncthreads();
    float acc = bias[o];
    for (int ci = 0; ci < 64; ++ci){
        const float* inp = dec_in + ((size_t)b*256 + ibase + ci)*1024;
        const float* wr = w_s + ci*9;
        #pragma unroll
        for (int kh = 0; kh < 3; ++kh){
            int ih = oh + kh - 1;
            if (ih < 0 || ih >= 32) continue;
            #pragma unroll
            for (int kw = 0; kw < 3; ++kw){
                int iw = ow + kw - 1;
                if (iw < 0 || iw >= 32) continue;
                acc = fmaf(inp[ih*32 + iw], wr[kh*3 + kw], acc);
            }
        }
    }
    out[idx] = acc;
}

// ---------------- up 1x1 convs (both branches), at 32x32, weights in LDS ----------------
__global__ __launch_bounds__(256) void k_up(const float* __restrict__ dec_out,
                                            const float* __restrict__ w0,
                                            const float* __restrict__ w1,
                                            float* __restrict__ uc0,
                                            float* __restrict__ uc1){
    int idx = blockIdx.x*256 + threadIdx.x;          // 1,310,720 (exact)
    int r = idx >= 655360;
    int j = idx - r*655360;
    int b   = j / 65536;
    int rem = j - b*65536;
    int o   = rem >> 10;
    int hw  = rem & 1023;
    __shared__ float w_s[64];
    if (threadIdx.x < 64) w_s[threadIdx.x] = (r ? w1 : w0)[o*64 + threadIdx.x];
    __syncthreads();
    const float* in = dec_out + (size_t)b*131072 + (size_t)(r*64)*1024 + hw;
    float acc = 0.f;
    #pragma unroll 8
    for (int i = 0; i < 64; ++i) acc = fmaf(in[(size_t)i*1024], w_s[i], acc);
    (r ? uc1 : uc0)[j] = acc;
}

// ---------------- fuse conv v2: tiled direct conv ----------------
// block = (b, 8x8 output tile); 256 thr = 4 o-subgroups x 64 spatial.
// LDS: 10x10 halo for all 128 in-ch (upsample folded). Each thread: 16 out-ch.
// Weights via wave-uniform scalar loads (readfirstlane og).
__global__ __launch_bounds__(256) void k_fus(const float* __restrict__ uc_act,
                                             const float* __restrict__ fid,
                                             const float* __restrict__ w,
                                             const float* __restrict__ bias,
                                             float* __restrict__ out){
    __shared__ float ts[12800];                      // 128 ch x 100 (10x10)
    int bt = blockIdx.x;                             // 640 = 10 b x 64 tiles
    int b  = bt >> 6, tIdx = bt & 63;
    int oh0 = (tIdx >> 3) << 3, ow0 = (tIdx & 7) << 3;
    int tid = threadIdx.x;

    for (int j = tid; j < 12800; j += 256){
        int i = j / 100, p = j - i*100;
        int ph = p / 10, pw = p - ph*10;
        int gh = oh0 + ph - 1, gw = ow0 + pw - 1;
        float v = 0.f;
        if (gh >= 0 && gh < 64 && gw >= 0 && gw < 64){
            if (i < 64) v = uc_act[(((size_t)b*64 + i) << 10) + ((gh >> 1) << 5) + (gw >> 1)];
            else        v = fid[(((size_t)b*64 + i - 64) << 12) + (gh << 6) + gw];
        }
        ts[j] = v;
    }
    __syncthreads();

    int og = __builtin_amdgcn_readfirstlane(tid >> 6);   // wave-uniform o-subgroup
    int sp = tid & 63, sh = sp >> 3, sw = sp & 7;
    const float* wb = w + (size_t)og * 18432;            // 16 o x 128 i x 9
    const float* bb = bias + og * 16;

    float acc[16];
    #pragma unroll
    for (int oo = 0; oo < 16; ++oo) acc[oo] = bb[oo];

    const float* tbase = ts + sh*10 + sw;
    #pragma unroll 2
    for (int i = 0; i < 128; ++i){
        const float* tp = tbase + i*100;
        float x0 = tp[0],  x1 = tp[1],  x2 = tp[2];
        float x3 = tp[10], x4 = tp[11], x5 = tp[12];
        float x6 = tp[20], x7 = tp[21], x8 = tp[22];
        const float* wpi = wb + i*9;
        #pragma unroll
        for (int oo = 0; oo < 16; ++oo){
            const float* wp = wpi + (size_t)oo*1152;
            acc[oo] = fmaf(x0, wp[0], acc[oo]);
            acc[oo] = fmaf(x1, wp[1], acc[oo]);
            acc[oo] = fmaf(x2, wp[2], acc[oo]);
            acc[oo] = fmaf(x3, wp[3], acc[oo]);
            acc[oo] = fmaf(x4, wp[4], acc[oo]);
            acc[oo] = fmaf(x5, wp[5], acc[oo]);
            acc[oo] = fmaf(x6, wp[6], acc[oo]);
            acc[oo] = fmaf(x7, wp[7], acc[oo]);
            acc[oo] = fmaf(x8, wp[8], acc[oo]);
        }
    }

    int oh = oh0 + sh, ow = ow0 + sw;
    float* op = out + ((size_t)b*64 + og*16)*4096 + (oh << 6) + ow;
    #pragma unroll
    for (int oo = 0; oo < 16; ++oo) op[(size_t)oo*4096] = acc[oo];
}

// ---------------- final 1x1 conv + SiLU, weights in LDS ----------------
__global__ __launch_bounds__(256) void k_final(const float* __restrict__ f0,
                                               const float* __restrict__ f1,
                                               const float* __restrict__ w,
                                               const float* __restrict__ bias,
                                               float* __restrict__ out){
    int idx = blockIdx.x*256 + threadIdx.x;          // 2,621,440 (exact)
    int b   = idx >> 18;
    int rem = idx & 262143;
    int o   = rem >> 12;
    int hw  = rem & 4095;
    __shared__ float w_s[128];
    if (threadIdx.x < 128) w_s[threadIdx.x] = w[o*128 + threadIdx.x];
    __syncthreads();
    const float* p0 = f0 + (size_t)b*262144 + hw;
    const float* p1 = f1 + (size_t)b*262144 + hw;
    float acc = bias[o];
    #pragma unroll 8
    for (int i = 0; i < 64; ++i) acc = fmaf(p0[(size_t)i*4096], w_s[i], acc);
    #pragma unroll 8
    for (int i = 0; i < 64; ++i) acc = fmaf(p1[(size_t)i*4096], w_s[64 + i], acc);
    out[idx] = silu_f(acc);
}

extern "C" void kernel_launch(void* const* d_in, const int* in_sizes, int n_in,
                              void* d_out, int out_size, void* d_ws, size_t ws_size,
                              hipStream_t stream) {
    const float* features = (const float*)d_in[0];
    const float* high     = (const float*)d_in[1];
    const float* fid0     = (const float*)d_in[2];
    const float* fid1     = (const float*)d_in[3];
    const float* bn_in_g  = (const float*)d_in[4];
    const float* bn_in_b  = (const float*)d_in[5];
    const float* down_w   = (const float*)d_in[6];
    const float* down_bn_g= (const float*)d_in[7];
    const float* down_bn_b= (const float*)d_in[8];
    const float* emb_w    = (const float*)d_in[9];
    const float* emb_b    = (const float*)d_in[10];
    const float* ln1_g    = (const float*)d_in[11];
    const float* ln1_b    = (const float*)d_in[12];
    const float* m_in_w   = (const float*)d_in[13];
    const float* m_conv_w = (const float*)d_in[14];
    const float* m_conv_b = (const float*)d_in[15];
    const float* m_xproj_w= (const float*)d_in[16];
    const float* m_dt_w   = (const float*)d_in[17];
    const float* m_dt_b   = (const float*)d_in[18];
    const float* m_A_log  = (const float*)d_in[19];
    const float* m_D      = (const float*)d_in[20];
    const float* m_out_w  = (const float*)d_in[21];
    const float* ln2_g    = (const float*)d_in[22];
    const float* ln2_b    = (const float*)d_in[23];
    const float* dec_w    = (const float*)d_in[24];
    const float* dec_b    = (const float*)d_in[25];
    const float* up0_w    = (const float*)d_in[26];
    const float* up0_bn_g = (const float*)d_in[27];
    const float* up0_bn_b = (const float*)d_in[28];
    const float* up1_w    = (const float*)d_in[29];
    const float* up1_bn_g = (const float*)d_in[30];
    const float* up1_bn_b = (const float*)d_in[31];
    const float* fus0_w   = (const float*)d_in[32];
    const float* fus0_b   = (const float*)d_in[33];
    const float* fus0_bn_g= (const float*)d_in[34];
    const float* fus0_bn_b= (const float*)d_in[35];
    const float* fus1_w   = (const float*)d_in[36];
    const float* fus1_b   = (const float*)d_in[37];
    const float* fus1_bn_g= (const float*)d_in[38];
    const float* fus1_bn_b= (const float*)d_in[39];
    const float* outf_w   = (const float*)d_in[40];
    const float* outf_b   = (const float*)d_in[41];

    float* ws = (float*)d_ws;
    float* out = (float*)d_out;

    float* st_in_sc  = ws + 0;    float* st_in_sh  = ws + 256;
    float* st_dn_sc  = ws + 512;  float* st_dn_sh  = ws + 896;
    float* st_u0_sc  = ws + 1536; float* st_u0_sh  = ws + 1600;
    float* st_u1_sc  = ws + 1664; float* st_u1_sh  = ws + 1728;
    float* st_f0_sc  = ws + 1792; float* st_f0_sh  = ws + 1856;
    float* st_f1_sc  = ws + 1920; float* st_f1_sh  = ws + 1984;

    float* fcat   = ws + OFF_FCAT;
    float* inT    = ws + OFF_INT;     // written after fcat is dead
    float* WdtT   = ws + OFF_WDTT;
    float* bcT    = ws + OFF_BCT;
    float* outT   = ws + OFF_OUTT;
    float* dec_in = ws + OFF_DECIN;
    float* down   = ws + OFF_DOWN;
    float* dec_out= ws + OFF_DECOUT;
    float* uc0    = ws + OFF_UC0;
    float* uc1    = ws + OFF_UC1;
    float* tok    = ws + OFF_TOK;
    float* fus0   = ws + OFF_FUS0;
    float* fus1   = ws + OFF_FUS1;

    // 1. build concat input
    k_fcat<<<38400, 256, 0, stream>>>(features, high, fcat);
    // 2. BN stats on fcat (240 ch, 64x64, N=10)
    k_bn_stats<<<240, 256, 0, stream>>>(fcat, bn_in_g, bn_in_b, st_in_sc, st_in_sh, 240, 12, 10);
    // 3. down conv (affine fused on reads)
    k_down<<<15360, 256, 0, stream>>>(fcat, down_w, st_in_sc, st_in_sh, down);
    // 4. transposed weight prep (fcat region now dead)
    k_prep<<<464, 256, 0, stream>>>(m_in_w, m_dt_w, m_xproj_w, m_out_w, inT, WdtT, bcT, outT);
    // 5. BN stats on down (384 ch, 32x32, N=10)
    k_bn_stats<<<384, 256, 0, stream>>>(down, down_bn_g, down_bn_b, st_dn_sc, st_dn_sh, 384, 10, 10);
    // 6. in-place BN+SiLU
    k_affine_silu<<<15360, 256, 0, stream>>>(down, st_dn_sc, st_dn_sh, 384, 10, 3932160);
    // 7. emb conv -> token layout
    k_emb<<<30720, 256, 0, stream>>>(down, emb_w, emb_b, tok);
    // 8. fused mamba v3
    k_mamba3<<<10240, 128, 0, stream>>>(tok, inT, m_conv_w, m_conv_b, WdtT, bcT,
                                        m_dt_b, m_A_log, m_D, outT,
                                        ln1_g, ln1_b, ln2_g, ln2_b, dec_in);
    // 9. dec conv
    k_dec<<<5120, 256, 0, stream>>>(dec_in, dec_w, dec_b, dec_out);
    // 10. up 1x1 convs at 32x32
    k_up<<<5120, 256, 0, stream>>>(dec_out, up0_w, up1_w, uc0, uc1);
    // 11. BN stats + activate uc0/uc1 (stats on upsampled map == stats at 32x32)
    k_bn_stats<<<64, 256, 0, stream>>>(uc0, up0_bn_g, up0_bn_b, st_u0_sc, st_u0_sh, 64, 10, 10);
    k_bn_stats<<<64, 256, 0, stream>>>(uc1, up1_bn_g, up1_bn_b, st_u1_sc, st_u1_sh, 64, 10, 10);
    k_affine_silu<<<2560, 256, 0, stream>>>(uc0, st_u0_sc, st_u0_sh, 64, 10, 655360);
    k_affine_silu<<<2560, 256, 0, stream>>>(uc1, st_u1_sc, st_u1_sh, 64, 10, 655360);
    // 12. fuse convs (tiled)
    k_fus<<<640, 256, 0, stream>>>(uc0, fid0, fus0_w, fus0_b, fus0);
    k_fus<<<640, 256, 0, stream>>>(uc1, fid1, fus1_w, fus1_b, fus1);
    // 13. BN stats + activate fus0/fus1
    k_bn_stats<<<64, 256, 0, stream>>>(fus0, fus0_bn_g, fus0_bn_b, st_f0_sc, st_f0_sh, 64, 12, 10);
    k_bn_stats<<<64, 256, 0, stream>>>(fus1, fus1_bn_g, fus1_bn_b, st_f1_sc, st_f1_sh, 64, 12, 10);
    k_affine_silu<<<10240, 256, 0, stream>>>(fus0, st_f0_sc, st_f0_sh, 64, 12, 2621440);
    k_affine_silu<<<10240, 256, 0, stream>>>(fus1, st_f1_sc, st_f1_sh, 64, 12, 2621440);
    // 14. final 1x1 + SiLU -> d_out
    k_final<<<10240, 256, 0, stream>>>(fus0, fus1, outf_w, outf_b, out);
}